// Round 9
// baseline (171.542 us; speedup 1.0000x reference)
//
#include <hip/hip_runtime.h>
#include <stdint.h>

#define HW 4096
#define CH 256
#define NB 4

typedef __attribute__((ext_vector_type(8))) short bf16x8;
typedef __attribute__((ext_vector_type(4))) float f32x4;
typedef __attribute__((ext_vector_type(16))) float f32x16;
typedef unsigned char u8;

__device__ __forceinline__ ushort f2bf(float f) {
    uint32_t u = __float_as_uint(f);
    u += 0x7fffu + ((u >> 16) & 1u);   // RNE
    return (ushort)(u >> 16);
}
// monotone float<->uint key (handles negatives) for atomicMax reductions
__device__ __forceinline__ uint fkey(float f) {
    uint b = __float_as_uint(f);
    return ((int)b < 0) ? ~b : (b | 0x80000000u);
}
__device__ __forceinline__ float finv(uint k) {
    uint b = (k & 0x80000000u) ? (k ^ 0x80000000u) : ~k;
    return __uint_as_float(b);
}

// ---------------------------------------------------------------------------
// prep: convert 3 weight matrices fp32->bf16, zero m2/Qmask key accumulators
__global__ __launch_bounds__(256) void prep_kernel(
    const float* __restrict__ Wq, const float* __restrict__ Wk,
    const float* __restrict__ Wv,
    ushort* __restrict__ Wq16, ushort* __restrict__ Wk16,
    ushort* __restrict__ Wv16, unsigned int* __restrict__ m2k,
    unsigned int* __restrict__ qmk) {
    int i = blockIdx.x * 256 + threadIdx.x;   // grid covers 65536
    Wq16[i] = f2bf(Wq[i]);
    Wk16[i] = f2bf(Wk[i]);
    Wv16[i] = f2bf(Wv[i]);
    if (i < NB * HW) qmk[i] = 0;              // fkey-min
    if (i < NB * 64) m2k[i] = 0;              // positive-float-min
}

// ---------------------------------------------------------------------------
// transpose + convert: fuse[b][c][hw] f32 -> fT[b][hw][c] bf16
__global__ __launch_bounds__(256) void transpose_kernel(
    const float* __restrict__ fuse, ushort* __restrict__ fT) {
    __shared__ float tile[32][65];
    const int b = blockIdx.z, c0 = blockIdx.y * 32, hw0 = blockIdx.x * 64;
    const int t = threadIdx.x;
    {
        const int i0 = t >> 4;
        const int j4 = (t & 15) * 4;
        const float* src = fuse + ((size_t)b * CH + c0) * HW + hw0;
        #pragma unroll
        for (int ii = 0; ii < 2; ++ii) {
            int i = i0 + ii * 16;
            float4 v = *(const float4*)(src + (size_t)i * HW + j4);
            tile[i][j4 + 0] = v.x; tile[i][j4 + 1] = v.y;
            tile[i][j4 + 2] = v.z; tile[i][j4 + 3] = v.w;
        }
    }
    __syncthreads();
    {
        const int j = t >> 2;
        const int i8 = (t & 3) * 8;
        __align__(16) ushort o8[8];
        #pragma unroll
        for (int k = 0; k < 8; ++k) o8[k] = f2bf(tile[i8 + k][j]);
        *(int4*)(fT + ((size_t)b * HW + hw0 + j) * CH + c0 + i8) = *(const int4*)o8;
    }
}

// ---------------------------------------------------------------------------
// conv1x1 GEMM: rows = out-channel o (A = W16[o][c]), cols = hw (B = fT[hw][c])
// MODE 0: K -> fp8 e4m3 32x32-FRAGMENT-MAJOR:
//   frag (b, kc=o>>4, blk=hw>>5) is 512B; lane = ((o>>3)&1)*32 + (hw&31),
//   elem = o&7.  (A/B operand layout of mfma_f32_32x32x16_fp8_fp8.)
// MODE 2: Q -> same layout + Q_mask block-reduce from fp32 acc -> qmout.
// MODE 1: V + mask epilogue (m2 read directly from m2key) -> f32 out.
template<int MODE>
__global__ __launch_bounds__(256) void conv_gemm_kernel(
    const ushort* __restrict__ fT, const ushort* __restrict__ W16,
    const float* __restrict__ bias,
    u8* __restrict__ out8, float* __restrict__ outf,
    const unsigned int* __restrict__ m2key,
    const unsigned int* __restrict__ qmkey,
    unsigned int* __restrict__ qmout) {
    __shared__ __align__(16) ushort Als[256][72];
    __shared__ __align__(16) ushort Bls[64][72];
    __shared__ float m2s[64];
    __shared__ float qred[4][4][64];   // [wave][o%4][hw-in-block]
    const int t = threadIdx.x;
    const int lane = t & 63, w = t >> 6;
    const int hw0 = blockIdx.x * 64;
    const int b = blockIdx.y;
    if (MODE == 1) {   // m2 is already fully reduced: direct read
        if (t < 64) m2s[t] = __uint_as_float(m2key[b * 64 + t]);
    }
    f32x4 acc[4][4] = {};   // [rf(o)][cf(hw)]
    for (int kc = 0; kc < 4; ++kc) {
        __syncthreads();
        #pragma unroll
        for (int i = 0; i < 8; ++i) {
            int q = t + 256 * i;
            int row = q >> 3, c8 = (q & 7) * 8;
            *(int4*)&Als[row][c8] =
                *(const int4*)(W16 + (size_t)row * CH + kc * 64 + c8);
        }
        #pragma unroll
        for (int i = 0; i < 2; ++i) {
            int q = t + 256 * i;
            int row = q >> 3, c8 = (q & 7) * 8;
            *(int4*)&Bls[row][c8] =
                *(const int4*)(fT + ((size_t)b * HW + hw0 + row) * CH + kc * 64 + c8);
        }
        __syncthreads();
        #pragma unroll
        for (int kk = 0; kk < 2; ++kk) {
            bf16x8 af[4];
            #pragma unroll
            for (int rf = 0; rf < 4; ++rf)
                af[rf] = *(const bf16x8*)&Als[w * 64 + rf * 16 + (lane & 15)]
                                             [kk * 32 + (lane >> 4) * 8];
            #pragma unroll
            for (int cf = 0; cf < 4; ++cf) {
                bf16x8 bf_ = *(const bf16x8*)&Bls[cf * 16 + (lane & 15)]
                                                 [kk * 32 + (lane >> 4) * 8];
                #pragma unroll
                for (int rf = 0; rf < 4; ++rf)
                    acc[rf][cf] = __builtin_amdgcn_mfma_f32_16x16x32_bf16(
                        af[rf], bf_, acc[rf][cf], 0, 0, 0);
            }
        }
    }
    float qmx[4][4];   // [cf][r] running max for Q_mask (MODE 2)
    if (MODE == 2) {
        #pragma unroll
        for (int cf = 0; cf < 4; ++cf)
            #pragma unroll
            for (int r = 0; r < 4; ++r) qmx[cf][r] = -3.4e38f;
    }
    #pragma unroll
    for (int rf = 0; rf < 4; ++rf) {
        const int ob = w * 64 + rf * 16 + (lane >> 4) * 4;  // o base (mult of 4)
        #pragma unroll
        for (int cf = 0; cf < 4; ++cf) {
            const int hw = hw0 + cf * 16 + (lane & 15);
            float v0 = acc[rf][cf][0] + bias[ob + 0];
            float v1 = acc[rf][cf][1] + bias[ob + 1];
            float v2 = acc[rf][cf][2] + bias[ob + 2];
            float v3 = acc[rf][cf][3] + bias[ob + 3];
            if (MODE != 1) {
                // pack 4 fp8 e4m3 (RNE, saturating) and store as one uint
                int u = __builtin_amdgcn_cvt_pk_fp8_f32(v0, v1, 0, false);
                u = __builtin_amdgcn_cvt_pk_fp8_f32(v2, v3, u, true);
                // 32x32-fragment-major index
                size_t idx = ((((size_t)b * 16 + (ob >> 4)) * 128 + (hw >> 5)) * 64
                              + ((ob >> 3) & 1) * 32 + (hw & 31)) * 8 + (ob & 7);
                *(unsigned int*)&out8[idx] = (unsigned int)u;
                if (MODE == 2) {
                    qmx[cf][0] = fmaxf(qmx[cf][0], v0);
                    qmx[cf][1] = fmaxf(qmx[cf][1], v1);
                    qmx[cf][2] = fmaxf(qmx[cf][2], v2);
                    qmx[cf][3] = fmaxf(qmx[cf][3], v3);
                }
            } else {
                const float mv = m2s[ob >> 2];
                const float vv[4] = {v0, v1, v2, v3};
                #pragma unroll
                for (int r = 0; r < 4; ++r) {   // o = ob+r, o%4 == r
                    float qm = finv(qmkey[r * HW + hw]);
                    outf[((size_t)b * CH + ob + r) * HW + hw] =
                        vv[r] * (1.0f + mv * qm);
                }
            }
        }
    }
    if (MODE == 2) {
        // reduce over row-groups: lanes l, l^16, l^32, l^48 share hw col & class r
        #pragma unroll
        for (int cf = 0; cf < 4; ++cf)
            #pragma unroll
            for (int r = 0; r < 4; ++r) {
                float v = qmx[cf][r];
                v = fmaxf(v, __shfl_xor(v, 16));
                v = fmaxf(v, __shfl_xor(v, 32));
                qmx[cf][r] = v;
            }
        __syncthreads();
        if (lane < 16) {
            #pragma unroll
            for (int cf = 0; cf < 4; ++cf)
                #pragma unroll
                for (int r = 0; r < 4; ++r)
                    qred[w][r][cf * 16 + lane] = qmx[cf][r];
        }
        __syncthreads();
        {
            const int r = t >> 6, h64 = t & 63;
            float v = fmaxf(fmaxf(qred[0][r][h64], qred[1][r][h64]),
                            fmaxf(qred[2][r][h64], qred[3][r][h64]));
            atomicMax(qmout + r * HW + hw0 + h64, fkey(v));
        }
    }
}

// ---------------------------------------------------------------------------
// scores, batch-per-lane: 256 threads = 4 waves (2wn x 2wm), block = 64n x 64m.
// One wave computes a 32x32 tile for ALL 4 batches via mfma_f32_32x32x16_fp8:
// acc_b[16] all live in-lane -> batch softmax is 100% lane-local, max-free
// (|s/16| <= ~0.6 for this data). Reduction target is only m2[b][hk]
// (max over n AND m within the 64-aligned hk block) -> 6 shfls + 4 atomics
// per wave. ZERO LDS, ZERO barriers. Fragments stream global->VGPR.
__global__ __launch_bounds__(256) void scores_bpl(
    const u8* __restrict__ Qw, const u8* __restrict__ Kw,
    unsigned int* __restrict__ m2k) {
    const int t = threadIdx.x;
    const int lane = t & 63, w = t >> 6;
    const int wn = w >> 1, wm = w & 1;
    // bijective XCD swizzle: xcd owns 8 n-rows; consecutive ids sweep m
    const int bid = blockIdx.x;
    const int xcd = bid & 7, j = bid >> 3;
    const int vn = xcd * 8 + (j >> 6), vm = j & 63;   // 64x64 tile grid
    const int blkn = vn * 2 + wn, blkm = vm * 2 + wm; // 32-row frag blocks

    const u8* qp = Qw + ((size_t)blkn * 64 + lane) * 8;
    const u8* kp = Kw + ((size_t)blkm * 64 + lane) * 8;

    f32x16 acc[4] = {};   // one 32x32 accumulator per batch
    #pragma unroll
    for (int kc = 0; kc < 16; ++kc) {
        long af[4], bf[4];
        #pragma unroll
        for (int b = 0; b < 4; ++b) {
            af[b] = *(const long*)(qp + (size_t)(b * 16 + kc) * 65536);
            bf[b] = *(const long*)(kp + (size_t)(b * 16 + kc) * 65536);
        }
        #pragma unroll
        for (int b = 0; b < 4; ++b)
            acc[b] = __builtin_amdgcn_mfma_f32_32x32x16_fp8_fp8(
                af[b], bf[b], acc[b], 0, 0, 0);
    }
    // lane-local batch softmax (max-free: scores bounded) + running max
    float pm0 = 0.f, pm1 = 0.f, pm2 = 0.f, pm3 = 0.f;
    #pragma unroll
    for (int jj = 0; jj < 16; ++jj) {
        float e0 = __expf(acc[0][jj] * 0.0625f);
        float e1 = __expf(acc[1][jj] * 0.0625f);
        float e2 = __expf(acc[2][jj] * 0.0625f);
        float e3 = __expf(acc[3][jj] * 0.0625f);
        float inv = __fdividef(1.0f, e0 + e1 + e2 + e3);
        pm0 = fmaxf(pm0, e0 * inv); pm1 = fmaxf(pm1, e1 * inv);
        pm2 = fmaxf(pm2, e2 * inv); pm3 = fmaxf(pm3, e3 * inv);
    }
    // full-wave max (covers the wave's 32 m-cols and both n-halves)
    #pragma unroll
    for (int off = 32; off >= 1; off >>= 1) {
        pm0 = fmaxf(pm0, __shfl_xor(pm0, off));
        pm1 = fmaxf(pm1, __shfl_xor(pm1, off));
        pm2 = fmaxf(pm2, __shfl_xor(pm2, off));
        pm3 = fmaxf(pm3, __shfl_xor(pm3, off));
    }
    if (lane == 0) {   // block m-range lies in exactly one hk (= vm)
        atomicMax(m2k + 0 * 64 + vm, __float_as_uint(pm0));
        atomicMax(m2k + 1 * 64 + vm, __float_as_uint(pm1));
        atomicMax(m2k + 2 * 64 + vm, __float_as_uint(pm2));
        atomicMax(m2k + 3 * 64 + vm, __float_as_uint(pm3));
    }
}

// ---------------------------------------------------------------------------
extern "C" void kernel_launch(void* const* d_in, const int* in_sizes, int n_in,
                              void* d_out, int out_size, void* d_ws, size_t ws_size,
                              hipStream_t stream) {
    const float* fuse = (const float*)d_in[0];
    const float* Wq   = (const float*)d_in[1];
    const float* bq   = (const float*)d_in[2];
    const float* Wk   = (const float*)d_in[3];
    const float* bk   = (const float*)d_in[4];
    const float* Wv   = (const float*)d_in[5];
    const float* bv   = (const float*)d_in[6];
    float* out = (float*)d_out;

    char* ws = (char*)d_ws;
    ushort* fT    = (ushort*)(ws);                       // 8 MiB
    ushort* Wq16  = (ushort*)(ws + 8388608);             // 128 KiB
    ushort* Wk16  = (ushort*)(ws + 8519680);             // 128 KiB
    ushort* Wv16  = (ushort*)(ws + 8650752);             // 128 KiB
    u8*     Qw8   = (u8*)    (ws + 8781824);             // 4 MiB (fp8 frag-major)
    u8*     Kw8   = (u8*)    (ws + 12976128);            // 4 MiB (fp8 frag-major)
    unsigned int* QMK = (unsigned int*)(ws + 17170432);  // 64 KiB (Q_mask keys)
    unsigned int* M2K = (unsigned int*)(ws + 17235968);  // 1 KiB (m2 keys)

    prep_kernel<<<256, 256, 0, stream>>>(Wq, Wk, Wv, Wq16, Wk16, Wv16, M2K, QMK);
    transpose_kernel<<<dim3(64, 8, NB), 256, 0, stream>>>(fuse, fT);
    conv_gemm_kernel<2><<<dim3(64, NB), 256, 0, stream>>>(   // Q + Q_mask
        fT, Wq16, bq, Qw8, nullptr, nullptr, nullptr, QMK);
    conv_gemm_kernel<0><<<dim3(64, NB), 256, 0, stream>>>(   // K
        fT, Wk16, bk, Kw8, nullptr, nullptr, nullptr, nullptr);
    scores_bpl<<<4096, 256, 0, stream>>>(Qw8, Kw8, M2K);
    conv_gemm_kernel<1><<<dim3(64, NB), 256, 0, stream>>>(   // V + mask epilogue
        fT, Wv16, bv, nullptr, out, M2K, QMK, nullptr);
}

// Round 10
// 114.931 us; speedup vs baseline: 1.4926x; 1.4926x over previous
//
#include <hip/hip_runtime.h>
#include <stdint.h>

#define HW 4096
#define CH 256
#define NB 4

typedef __attribute__((ext_vector_type(8))) short bf16x8;
typedef __attribute__((ext_vector_type(4))) float f32x4;
typedef unsigned char u8;

__device__ __forceinline__ ushort f2bf(float f) {
    uint32_t u = __float_as_uint(f);
    u += 0x7fffu + ((u >> 16) & 1u);   // RNE
    return (ushort)(u >> 16);
}
// monotone float<->uint key (handles negatives) for atomicMax reductions
__device__ __forceinline__ uint fkey(float f) {
    uint b = __float_as_uint(f);
    return ((int)b < 0) ? ~b : (b | 0x80000000u);
}
__device__ __forceinline__ float finv(uint k) {
    uint b = (k & 0x80000000u) ? (k ^ 0x80000000u) : ~k;
    return __uint_as_float(b);
}

// ---------------------------------------------------------------------------
// prep: convert 3 weight matrices fp32->bf16, zero m2/Qmask key accumulators
__global__ __launch_bounds__(256) void prep_kernel(
    const float* __restrict__ Wq, const float* __restrict__ Wk,
    const float* __restrict__ Wv,
    ushort* __restrict__ Wq16, ushort* __restrict__ Wk16,
    ushort* __restrict__ Wv16, unsigned int* __restrict__ m2k,
    unsigned int* __restrict__ qmk) {
    int i = blockIdx.x * 256 + threadIdx.x;   // grid covers 65536
    Wq16[i] = f2bf(Wq[i]);
    Wk16[i] = f2bf(Wk[i]);
    Wv16[i] = f2bf(Wv[i]);
    if (i < NB * HW) qmk[i] = 0;              // fkey-min
    if (i < NB * 64) m2k[i] = 0;              // positive-float-min
}

// ---------------------------------------------------------------------------
// transpose + convert: fuse[b][c][hw] f32 -> fT[b][hw][c] bf16
__global__ __launch_bounds__(256) void transpose_kernel(
    const float* __restrict__ fuse, ushort* __restrict__ fT) {
    __shared__ float tile[32][65];
    const int b = blockIdx.z, c0 = blockIdx.y * 32, hw0 = blockIdx.x * 64;
    const int t = threadIdx.x;
    {
        const int i0 = t >> 4;
        const int j4 = (t & 15) * 4;
        const float* src = fuse + ((size_t)b * CH + c0) * HW + hw0;
        #pragma unroll
        for (int ii = 0; ii < 2; ++ii) {
            int i = i0 + ii * 16;
            float4 v = *(const float4*)(src + (size_t)i * HW + j4);
            tile[i][j4 + 0] = v.x; tile[i][j4 + 1] = v.y;
            tile[i][j4 + 2] = v.z; tile[i][j4 + 3] = v.w;
        }
    }
    __syncthreads();
    {
        const int j = t >> 2;
        const int i8 = (t & 3) * 8;
        __align__(16) ushort o8[8];
        #pragma unroll
        for (int k = 0; k < 8; ++k) o8[k] = f2bf(tile[i8 + k][j]);
        *(int4*)(fT + ((size_t)b * HW + hw0 + j) * CH + c0 + i8) = *(const int4*)o8;
    }
}

// ---------------------------------------------------------------------------
// conv1x1 GEMM: rows = out-channel o (A = W16[o][c]), cols = hw (B = fT[hw][c])
// MODE 0: K -> fp8 e4m3 16x16-FRAGMENT-MAJOR F[b][o>>5][hw>>4][lane][8]:
//   lane = ((o>>3)&3)*16 + (hw&15), elem = o&7 (R8-validated layout).
// MODE 2: Q -> same layout + Q_mask block-reduce from fp32 acc -> qmout.
// MODE 1: V + mask epilogue (m2 read directly from m2key) -> f32 out.
template<int MODE>
__global__ __launch_bounds__(256) void conv_gemm_kernel(
    const ushort* __restrict__ fT, const ushort* __restrict__ W16,
    const float* __restrict__ bias,
    u8* __restrict__ out8, float* __restrict__ outf,
    const unsigned int* __restrict__ m2key,
    const unsigned int* __restrict__ qmkey,
    unsigned int* __restrict__ qmout) {
    __shared__ __align__(16) ushort Als[256][72];
    __shared__ __align__(16) ushort Bls[64][72];
    __shared__ float m2s[64];
    __shared__ float qred[4][4][64];   // [wave][o%4][hw-in-block]
    const int t = threadIdx.x;
    const int lane = t & 63, w = t >> 6;
    const int hw0 = blockIdx.x * 64;
    const int b = blockIdx.y;
    if (MODE == 1) {   // m2 is already fully reduced: direct read
        if (t < 64) m2s[t] = __uint_as_float(m2key[b * 64 + t]);
    }
    f32x4 acc[4][4] = {};   // [rf(o)][cf(hw)]
    for (int kc = 0; kc < 4; ++kc) {
        __syncthreads();
        #pragma unroll
        for (int i = 0; i < 8; ++i) {
            int q = t + 256 * i;
            int row = q >> 3, c8 = (q & 7) * 8;
            *(int4*)&Als[row][c8] =
                *(const int4*)(W16 + (size_t)row * CH + kc * 64 + c8);
        }
        #pragma unroll
        for (int i = 0; i < 2; ++i) {
            int q = t + 256 * i;
            int row = q >> 3, c8 = (q & 7) * 8;
            *(int4*)&Bls[row][c8] =
                *(const int4*)(fT + ((size_t)b * HW + hw0 + row) * CH + kc * 64 + c8);
        }
        __syncthreads();
        #pragma unroll
        for (int kk = 0; kk < 2; ++kk) {
            bf16x8 af[4];
            #pragma unroll
            for (int rf = 0; rf < 4; ++rf)
                af[rf] = *(const bf16x8*)&Als[w * 64 + rf * 16 + (lane & 15)]
                                             [kk * 32 + (lane >> 4) * 8];
            #pragma unroll
            for (int cf = 0; cf < 4; ++cf) {
                bf16x8 bf_ = *(const bf16x8*)&Bls[cf * 16 + (lane & 15)]
                                                 [kk * 32 + (lane >> 4) * 8];
                #pragma unroll
                for (int rf = 0; rf < 4; ++rf)
                    acc[rf][cf] = __builtin_amdgcn_mfma_f32_16x16x32_bf16(
                        af[rf], bf_, acc[rf][cf], 0, 0, 0);
            }
        }
    }
    float qmx[4][4];   // [cf][r] running max for Q_mask (MODE 2)
    if (MODE == 2) {
        #pragma unroll
        for (int cf = 0; cf < 4; ++cf)
            #pragma unroll
            for (int r = 0; r < 4; ++r) qmx[cf][r] = -3.4e38f;
    }
    #pragma unroll
    for (int rf = 0; rf < 4; ++rf) {
        const int ob = w * 64 + rf * 16 + (lane >> 4) * 4;  // o base (mult of 4)
        #pragma unroll
        for (int cf = 0; cf < 4; ++cf) {
            const int hw = hw0 + cf * 16 + (lane & 15);
            float v0 = acc[rf][cf][0] + bias[ob + 0];
            float v1 = acc[rf][cf][1] + bias[ob + 1];
            float v2 = acc[rf][cf][2] + bias[ob + 2];
            float v3 = acc[rf][cf][3] + bias[ob + 3];
            if (MODE != 1) {
                // pack 4 fp8 e4m3 (RNE, saturating) and store as one uint
                int u = __builtin_amdgcn_cvt_pk_fp8_f32(v0, v1, 0, false);
                u = __builtin_amdgcn_cvt_pk_fp8_f32(v2, v3, u, true);
                // 16x16-fragment-major index (R8-validated)
                size_t idx = ((((size_t)b * 8 + (ob >> 5)) * 256 + (hw >> 4)) * 64
                              + ((ob >> 3) & 3) * 16 + (hw & 15)) * 8 + (ob & 7);
                *(unsigned int*)&out8[idx] = (unsigned int)u;
                if (MODE == 2) {
                    qmx[cf][0] = fmaxf(qmx[cf][0], v0);
                    qmx[cf][1] = fmaxf(qmx[cf][1], v1);
                    qmx[cf][2] = fmaxf(qmx[cf][2], v2);
                    qmx[cf][3] = fmaxf(qmx[cf][3], v3);
                }
            } else {
                const float mv = m2s[ob >> 2];
                const float vv[4] = {v0, v1, v2, v3};
                #pragma unroll
                for (int r = 0; r < 4; ++r) {   // o = ob+r, o%4 == r
                    float qm = finv(qmkey[r * HW + hw]);
                    outf[((size_t)b * CH + ob + r) * HW + hw] =
                        vv[r] * (1.0f + mv * qm);
                }
            }
        }
    }
    if (MODE == 2) {
        // reduce over row-groups: lanes l, l^16, l^32, l^48 share hw col & class r
        #pragma unroll
        for (int cf = 0; cf < 4; ++cf)
            #pragma unroll
            for (int r = 0; r < 4; ++r) {
                float v = qmx[cf][r];
                v = fmaxf(v, __shfl_xor(v, 16));
                v = fmaxf(v, __shfl_xor(v, 32));
                qmx[cf][r] = v;
            }
        __syncthreads();
        if (lane < 16) {
            #pragma unroll
            for (int cf = 0; cf < 4; ++cf)
                #pragma unroll
                for (int r = 0; r < 4; ++r)
                    qred[w][r][cf * 16 + lane] = qmx[cf][r];
        }
        __syncthreads();
        {
            const int r = t >> 6, h64 = t & 63;
            float v = fmaxf(fmaxf(qred[0][r][h64], qred[1][r][h64]),
                            fmaxf(qred[2][r][h64], qred[3][r][h64]));
            atomicMax(qmout + r * HW + hw0 + h64, fkey(v));
        }
    }
}

// ---------------------------------------------------------------------------
// scores64: 64n x 64m tile per 256-thread block; wave w = batch w, ALL 4
// waves compute the SAME (n,m) tile -> cross-batch exchange is intra-block.
// K-loop: R8's fp8 fragment streaming (8 loads : 16 MFMA per kc, no barriers).
// Epilogue: 4 substeps through 16KB EX[4][4][64] f32x4 (lane-contiguous,
// conflict-free); thread (w,lane) owns mf=w -> each softmax item computed
// exactly once (64 exp/thread); block-reduce -> 4 atomics (m2 only, R9 idea).
// Small footprint (16.6KB LDS, 256 thr) -> ~4 blocks/CU: one block's epilogue
// barriers overlap other blocks' k-loops.
__global__ __launch_bounds__(256) void scores64(
    const u8* __restrict__ Qw, const u8* __restrict__ Kw,
    unsigned int* __restrict__ m2k) {
    __shared__ __align__(16) f32x4 EX[4][4][64];   // [b][mf][lane] 16 KB
    __shared__ float red[4][4];                    // [wave][batch]
    const int t = threadIdx.x;
    const int lane = t & 63, w = t >> 6;           // w = batch
    // XCD-rectangle swizzle: xcd gets 16n x 32m tiles (Q 1MB + K 2MB < 4MB L2)
    const int bid = blockIdx.x;
    const int xcd = bid & 7, j = bid >> 3;
    const int vn = (xcd & 3) * 16 + (j & 15);
    const int vm = (xcd >> 2) * 32 + (j >> 4);

    const u8* qp = Qw + (((size_t)w * 8) * 256 + vn * 4) * 512 + lane * 8;
    const u8* kp = Kw + (((size_t)w * 8) * 256 + vm * 4) * 512 + lane * 8;

    f32x4 acc[4][4] = {};   // [nf][mf]
    #pragma unroll
    for (int kc = 0; kc < 8; ++kc) {
        long af[4], bf[4];
        #pragma unroll
        for (int nf = 0; nf < 4; ++nf)
            af[nf] = *(const long*)(qp + (size_t)kc * 131072 + nf * 512);
        #pragma unroll
        for (int mf = 0; mf < 4; ++mf)
            bf[mf] = *(const long*)(kp + (size_t)kc * 131072 + mf * 512);
        #pragma unroll
        for (int mf = 0; mf < 4; ++mf)
            #pragma unroll
            for (int nf = 0; nf < 4; ++nf)
                acc[nf][mf] = __builtin_amdgcn_mfma_f32_16x16x32_fp8_fp8(
                    af[nf], bf[mf], acc[nf][mf], 0, 0, 0);
    }

    // ---- exchange + softmax: 4 substeps over nf ----
    float pmAll[4] = {0.f, 0.f, 0.f, 0.f};
    #pragma unroll
    for (int nf = 0; nf < 4; ++nf) {
        if (nf) __syncthreads();          // previous substep's reads done
        #pragma unroll
        for (int mf = 0; mf < 4; ++mf)
            EX[w][mf][lane] = acc[nf][mf];
        __syncthreads();
        f32x4 sv[4];
        #pragma unroll
        for (int b2 = 0; b2 < 4; ++b2)
            sv[b2] = EX[b2][w][lane];     // this thread owns mf = w
        #pragma unroll
        for (int jj = 0; jj < 4; ++jj) {
            float e0 = __expf(sv[0][jj] * 0.0625f);
            float e1 = __expf(sv[1][jj] * 0.0625f);
            float e2 = __expf(sv[2][jj] * 0.0625f);
            float e3 = __expf(sv[3][jj] * 0.0625f);
            float inv = __fdividef(1.0f, e0 + e1 + e2 + e3);
            pmAll[0] = fmaxf(pmAll[0], e0 * inv);
            pmAll[1] = fmaxf(pmAll[1], e1 * inv);
            pmAll[2] = fmaxf(pmAll[2], e2 * inv);
            pmAll[3] = fmaxf(pmAll[3], e3 * inv);
        }
    }
    // wave reduce (max over all lanes), then block reduce, 4 atomics
    #pragma unroll
    for (int off = 32; off >= 1; off >>= 1) {
        pmAll[0] = fmaxf(pmAll[0], __shfl_xor(pmAll[0], off));
        pmAll[1] = fmaxf(pmAll[1], __shfl_xor(pmAll[1], off));
        pmAll[2] = fmaxf(pmAll[2], __shfl_xor(pmAll[2], off));
        pmAll[3] = fmaxf(pmAll[3], __shfl_xor(pmAll[3], off));
    }
    __syncthreads();   // EX reads done; red aliases fresh region anyway
    if (lane == 0) {
        #pragma unroll
        for (int b2 = 0; b2 < 4; ++b2) red[w][b2] = pmAll[b2];
    }
    __syncthreads();
    if (t < 4) {   // t = batch
        float v = fmaxf(fmaxf(red[0][t], red[1][t]),
                        fmaxf(red[2][t], red[3][t]));
        atomicMax(m2k + t * 64 + vm, __float_as_uint(v));  // soft > 0
    }
}

// ---------------------------------------------------------------------------
extern "C" void kernel_launch(void* const* d_in, const int* in_sizes, int n_in,
                              void* d_out, int out_size, void* d_ws, size_t ws_size,
                              hipStream_t stream) {
    const float* fuse = (const float*)d_in[0];
    const float* Wq   = (const float*)d_in[1];
    const float* bq   = (const float*)d_in[2];
    const float* Wk   = (const float*)d_in[3];
    const float* bk   = (const float*)d_in[4];
    const float* Wv   = (const float*)d_in[5];
    const float* bv   = (const float*)d_in[6];
    float* out = (float*)d_out;

    char* ws = (char*)d_ws;
    ushort* fT    = (ushort*)(ws);                       // 8 MiB
    ushort* Wq16  = (ushort*)(ws + 8388608);             // 128 KiB
    ushort* Wk16  = (ushort*)(ws + 8519680);             // 128 KiB
    ushort* Wv16  = (ushort*)(ws + 8650752);             // 128 KiB
    u8*     Qw8   = (u8*)    (ws + 8781824);             // 4 MiB (fp8 frag-major)
    u8*     Kw8   = (u8*)    (ws + 12976128);            // 4 MiB (fp8 frag-major)
    unsigned int* QMK = (unsigned int*)(ws + 17170432);  // 64 KiB (Q_mask keys)
    unsigned int* M2K = (unsigned int*)(ws + 17235968);  // 1 KiB (m2 keys)

    prep_kernel<<<256, 256, 0, stream>>>(Wq, Wk, Wv, Wq16, Wk16, Wv16, M2K, QMK);
    transpose_kernel<<<dim3(64, 8, NB), 256, 0, stream>>>(fuse, fT);
    conv_gemm_kernel<2><<<dim3(64, NB), 256, 0, stream>>>(   // Q + Q_mask
        fT, Wq16, bq, Qw8, nullptr, nullptr, nullptr, QMK);
    conv_gemm_kernel<0><<<dim3(64, NB), 256, 0, stream>>>(   // K
        fT, Wk16, bk, Kw8, nullptr, nullptr, nullptr, nullptr);
    scores64<<<4096, 256, 0, stream>>>(Qw8, Kw8, M2K);
    conv_gemm_kernel<1><<<dim3(64, NB), 256, 0, stream>>>(   // V + mask epilogue
        fT, Wv16, bv, nullptr, out, M2K, QMK, nullptr);
}

// Round 11
// 113.123 us; speedup vs baseline: 1.5164x; 1.0160x over previous
//
#include <hip/hip_runtime.h>
#include <stdint.h>

#define HW 4096
#define CH 256
#define NB 4

typedef __attribute__((ext_vector_type(8))) short bf16x8;
typedef __attribute__((ext_vector_type(4))) float f32x4;
typedef unsigned char u8;

__device__ __forceinline__ ushort f2bf(float f) {
    uint32_t u = __float_as_uint(f);
    u += 0x7fffu + ((u >> 16) & 1u);   // RNE
    return (ushort)(u >> 16);
}
// monotone float<->uint key (handles negatives) for atomicMax reductions
__device__ __forceinline__ uint fkey(float f) {
    uint b = __float_as_uint(f);
    return ((int)b < 0) ? ~b : (b | 0x80000000u);
}
__device__ __forceinline__ float finv(uint k) {
    uint b = (k & 0x80000000u) ? (k ^ 0x80000000u) : ~k;
    return __uint_as_float(b);
}

// ---------------------------------------------------------------------------
// prep: convert 3 weight matrices fp32->bf16, zero m2/Qmask key accumulators
__global__ __launch_bounds__(256) void prep_kernel(
    const float* __restrict__ Wq, const float* __restrict__ Wk,
    const float* __restrict__ Wv,
    ushort* __restrict__ Wq16, ushort* __restrict__ Wk16,
    ushort* __restrict__ Wv16, unsigned int* __restrict__ m2k,
    unsigned int* __restrict__ qmk) {
    int i = blockIdx.x * 256 + threadIdx.x;   // grid covers 65536
    Wq16[i] = f2bf(Wq[i]);
    Wk16[i] = f2bf(Wk[i]);
    Wv16[i] = f2bf(Wv[i]);
    if (i < NB * HW) qmk[i] = 0;              // fkey-min
    if (i < NB * 64) m2k[i] = 0;              // positive-float-min
}

// ---------------------------------------------------------------------------
// transpose + convert: fuse[b][c][hw] f32 -> fT[b][hw][c] bf16
__global__ __launch_bounds__(256) void transpose_kernel(
    const float* __restrict__ fuse, ushort* __restrict__ fT) {
    __shared__ float tile[32][65];
    const int b = blockIdx.z, c0 = blockIdx.y * 32, hw0 = blockIdx.x * 64;
    const int t = threadIdx.x;
    {
        const int i0 = t >> 4;
        const int j4 = (t & 15) * 4;
        const float* src = fuse + ((size_t)b * CH + c0) * HW + hw0;
        #pragma unroll
        for (int ii = 0; ii < 2; ++ii) {
            int i = i0 + ii * 16;
            float4 v = *(const float4*)(src + (size_t)i * HW + j4);
            tile[i][j4 + 0] = v.x; tile[i][j4 + 1] = v.y;
            tile[i][j4 + 2] = v.z; tile[i][j4 + 3] = v.w;
        }
    }
    __syncthreads();
    {
        const int j = t >> 2;
        const int i8 = (t & 3) * 8;
        __align__(16) ushort o8[8];
        #pragma unroll
        for (int k = 0; k < 8; ++k) o8[k] = f2bf(tile[i8 + k][j]);
        *(int4*)(fT + ((size_t)b * HW + hw0 + j) * CH + c0 + i8) = *(const int4*)o8;
    }
}

// ---------------------------------------------------------------------------
// conv1x1 GEMM: rows = out-channel o (A = W16[o][c]), cols = hw (B = fT[hw][c])
// MODE 0: K -> fp8 e4m3 16x16-FRAGMENT-MAJOR F[b][o>>5][hw>>4][lane][8]:
//   lane = ((o>>3)&3)*16 + (hw&15), elem = o&7 (R8-validated layout).
// MODE 2: Q -> same layout + Q_mask block-reduce from fp32 acc -> qmout.
// MODE 1: V + mask epilogue (m2 read directly from m2key) -> f32 out.
template<int MODE>
__global__ __launch_bounds__(256) void conv_gemm_kernel(
    const ushort* __restrict__ fT, const ushort* __restrict__ W16,
    const float* __restrict__ bias,
    u8* __restrict__ out8, float* __restrict__ outf,
    const unsigned int* __restrict__ m2key,
    const unsigned int* __restrict__ qmkey,
    unsigned int* __restrict__ qmout) {
    __shared__ __align__(16) ushort Als[256][72];
    __shared__ __align__(16) ushort Bls[64][72];
    __shared__ float m2s[64];
    __shared__ float qred[4][4][64];   // [wave][o%4][hw-in-block]
    const int t = threadIdx.x;
    const int lane = t & 63, w = t >> 6;
    const int hw0 = blockIdx.x * 64;
    const int b = blockIdx.y;
    if (MODE == 1) {   // m2 is already fully reduced: direct read
        if (t < 64) m2s[t] = __uint_as_float(m2key[b * 64 + t]);
    }
    f32x4 acc[4][4] = {};   // [rf(o)][cf(hw)]
    for (int kc = 0; kc < 4; ++kc) {
        __syncthreads();
        #pragma unroll
        for (int i = 0; i < 8; ++i) {
            int q = t + 256 * i;
            int row = q >> 3, c8 = (q & 7) * 8;
            *(int4*)&Als[row][c8] =
                *(const int4*)(W16 + (size_t)row * CH + kc * 64 + c8);
        }
        #pragma unroll
        for (int i = 0; i < 2; ++i) {
            int q = t + 256 * i;
            int row = q >> 3, c8 = (q & 7) * 8;
            *(int4*)&Bls[row][c8] =
                *(const int4*)(fT + ((size_t)b * HW + hw0 + row) * CH + kc * 64 + c8);
        }
        __syncthreads();
        #pragma unroll
        for (int kk = 0; kk < 2; ++kk) {
            bf16x8 af[4];
            #pragma unroll
            for (int rf = 0; rf < 4; ++rf)
                af[rf] = *(const bf16x8*)&Als[w * 64 + rf * 16 + (lane & 15)]
                                             [kk * 32 + (lane >> 4) * 8];
            #pragma unroll
            for (int cf = 0; cf < 4; ++cf) {
                bf16x8 bf_ = *(const bf16x8*)&Bls[cf * 16 + (lane & 15)]
                                                 [kk * 32 + (lane >> 4) * 8];
                #pragma unroll
                for (int rf = 0; rf < 4; ++rf)
                    acc[rf][cf] = __builtin_amdgcn_mfma_f32_16x16x32_bf16(
                        af[rf], bf_, acc[rf][cf], 0, 0, 0);
            }
        }
    }
    float qmx[4][4];   // [cf][r] running max for Q_mask (MODE 2)
    if (MODE == 2) {
        #pragma unroll
        for (int cf = 0; cf < 4; ++cf)
            #pragma unroll
            for (int r = 0; r < 4; ++r) qmx[cf][r] = -3.4e38f;
    }
    #pragma unroll
    for (int rf = 0; rf < 4; ++rf) {
        const int ob = w * 64 + rf * 16 + (lane >> 4) * 4;  // o base (mult of 4)
        #pragma unroll
        for (int cf = 0; cf < 4; ++cf) {
            const int hw = hw0 + cf * 16 + (lane & 15);
            float v0 = acc[rf][cf][0] + bias[ob + 0];
            float v1 = acc[rf][cf][1] + bias[ob + 1];
            float v2 = acc[rf][cf][2] + bias[ob + 2];
            float v3 = acc[rf][cf][3] + bias[ob + 3];
            if (MODE != 1) {
                // pack 4 fp8 e4m3 (RNE, saturating) and store as one uint
                int u = __builtin_amdgcn_cvt_pk_fp8_f32(v0, v1, 0, false);
                u = __builtin_amdgcn_cvt_pk_fp8_f32(v2, v3, u, true);
                // 16x16-fragment-major index (R8-validated)
                size_t idx = ((((size_t)b * 8 + (ob >> 5)) * 256 + (hw >> 4)) * 64
                              + ((ob >> 3) & 3) * 16 + (hw & 15)) * 8 + (ob & 7);
                *(unsigned int*)&out8[idx] = (unsigned int)u;
                if (MODE == 2) {
                    qmx[cf][0] = fmaxf(qmx[cf][0], v0);
                    qmx[cf][1] = fmaxf(qmx[cf][1], v1);
                    qmx[cf][2] = fmaxf(qmx[cf][2], v2);
                    qmx[cf][3] = fmaxf(qmx[cf][3], v3);
                }
            } else {
                const float mv = m2s[ob >> 2];
                const float vv[4] = {v0, v1, v2, v3};
                #pragma unroll
                for (int r = 0; r < 4; ++r) {   // o = ob+r, o%4 == r
                    float qm = finv(qmkey[r * HW + hw]);
                    outf[((size_t)b * CH + ob + r) * HW + hw] =
                        vv[r] * (1.0f + mv * qm);
                }
            }
        }
    }
    if (MODE == 2) {
        // reduce over row-groups: lanes l, l^16, l^32, l^48 share hw col & class r
        #pragma unroll
        for (int cf = 0; cf < 4; ++cf)
            #pragma unroll
            for (int r = 0; r < 4; ++r) {
                float v = qmx[cf][r];
                v = fmaxf(v, __shfl_xor(v, 16));
                v = fmaxf(v, __shfl_xor(v, 32));
                qmx[cf][r] = v;
            }
        __syncthreads();
        if (lane < 16) {
            #pragma unroll
            for (int cf = 0; cf < 4; ++cf)
                #pragma unroll
                for (int r = 0; r < 4; ++r)
                    qred[w][r][cf * 16 + lane] = qmx[cf][r];
        }
        __syncthreads();
        {
            const int r = t >> 6, h64 = t & 63;
            float v = fmaxf(fmaxf(qred[0][r][h64], qred[1][r][h64]),
                            fmaxf(qred[2][r][h64], qred[3][r][h64]));
            atomicMax(qmout + r * HW + hw0 + h64, fkey(v));
        }
    }
}

// ---------------------------------------------------------------------------
// scores64: 64n x 64m tile per 256-thread block; wave w = batch w, ALL 4
// waves compute the SAME (n,m) tile -> cross-batch exchange is intra-block.
// R11: __launch_bounds__(256,4) lifts the VGPR cap to 128 (R10's compiler
// choice of 60 VGPR left ~2 free regs -> loads serialized on vmcnt) and the
// k-loop is an explicit depth-2 register double-buffer in static straight-line
// form (16 loads in flight; each kc's MFMA covers the next kc's L2 latency).
// Epilogue (R10-verified): 16KB EX exchange, each softmax item once,
// 4 atomics/block (m2 only).
__global__ __launch_bounds__(256, 4) void scores64(
    const u8* __restrict__ Qw, const u8* __restrict__ Kw,
    unsigned int* __restrict__ m2k) {
    __shared__ __align__(16) f32x4 EX[4][4][64];   // [b][mf][lane] 16 KB
    __shared__ float red[4][4];                    // [wave][batch]
    const int t = threadIdx.x;
    const int lane = t & 63, w = t >> 6;           // w = batch
    // XCD-rectangle swizzle: xcd gets 16n x 32m tiles (Q 1MB + K 2MB < 4MB L2)
    const int bid = blockIdx.x;
    const int xcd = bid & 7, j = bid >> 3;
    const int vn = (xcd & 3) * 16 + (j & 15);
    const int vm = (xcd >> 2) * 32 + (j >> 4);

    const u8* qp = Qw + (((size_t)w * 8) * 256 + vn * 4) * 512 + lane * 8;
    const u8* kp = Kw + (((size_t)w * 8) * 256 + vm * 4) * 512 + lane * 8;

    f32x4 acc[4][4] = {};   // [nf][mf]
    long a0[4], b0[4], a1[4], b1[4];   // depth-2 fragment double-buffer
#define LOADF(A, B, KC)                                                  \
    _Pragma("unroll") for (int i = 0; i < 4; ++i) {                      \
        A[i] = *(const long*)(qp + (size_t)(KC) * 131072 + i * 512);     \
        B[i] = *(const long*)(kp + (size_t)(KC) * 131072 + i * 512);     \
    }
#define MFMAS(A, B)                                                      \
    _Pragma("unroll") for (int mf = 0; mf < 4; ++mf)                     \
        _Pragma("unroll") for (int nf = 0; nf < 4; ++nf)                 \
            acc[nf][mf] = __builtin_amdgcn_mfma_f32_16x16x32_fp8_fp8(    \
                A[nf], B[mf], acc[nf][mf], 0, 0, 0);
    LOADF(a0, b0, 0)
    LOADF(a1, b1, 1)
    MFMAS(a0, b0) LOADF(a0, b0, 2)
    MFMAS(a1, b1) LOADF(a1, b1, 3)
    MFMAS(a0, b0) LOADF(a0, b0, 4)
    MFMAS(a1, b1) LOADF(a1, b1, 5)
    MFMAS(a0, b0) LOADF(a0, b0, 6)
    MFMAS(a1, b1) LOADF(a1, b1, 7)
    MFMAS(a0, b0)
    MFMAS(a1, b1)
#undef LOADF
#undef MFMAS

    // ---- exchange + softmax: 4 substeps over nf ----
    float pmAll[4] = {0.f, 0.f, 0.f, 0.f};
    #pragma unroll
    for (int nf = 0; nf < 4; ++nf) {
        if (nf) __syncthreads();          // previous substep's reads done
        #pragma unroll
        for (int mf = 0; mf < 4; ++mf)
            EX[w][mf][lane] = acc[nf][mf];
        __syncthreads();
        f32x4 sv[4];
        #pragma unroll
        for (int b2 = 0; b2 < 4; ++b2)
            sv[b2] = EX[b2][w][lane];     // this thread owns mf = w
        #pragma unroll
        for (int jj = 0; jj < 4; ++jj) {
            float e0 = __expf(sv[0][jj] * 0.0625f);
            float e1 = __expf(sv[1][jj] * 0.0625f);
            float e2 = __expf(sv[2][jj] * 0.0625f);
            float e3 = __expf(sv[3][jj] * 0.0625f);
            float inv = __fdividef(1.0f, e0 + e1 + e2 + e3);
            pmAll[0] = fmaxf(pmAll[0], e0 * inv);
            pmAll[1] = fmaxf(pmAll[1], e1 * inv);
            pmAll[2] = fmaxf(pmAll[2], e2 * inv);
            pmAll[3] = fmaxf(pmAll[3], e3 * inv);
        }
    }
    // wave reduce (max over all lanes), then block reduce, 4 atomics
    #pragma unroll
    for (int off = 32; off >= 1; off >>= 1) {
        pmAll[0] = fmaxf(pmAll[0], __shfl_xor(pmAll[0], off));
        pmAll[1] = fmaxf(pmAll[1], __shfl_xor(pmAll[1], off));
        pmAll[2] = fmaxf(pmAll[2], __shfl_xor(pmAll[2], off));
        pmAll[3] = fmaxf(pmAll[3], __shfl_xor(pmAll[3], off));
    }
    __syncthreads();   // EX reads done; red aliases fresh region anyway
    if (lane == 0) {
        #pragma unroll
        for (int b2 = 0; b2 < 4; ++b2) red[w][b2] = pmAll[b2];
    }
    __syncthreads();
    if (t < 4) {   // t = batch
        float v = fmaxf(fmaxf(red[0][t], red[1][t]),
                        fmaxf(red[2][t], red[3][t]));
        atomicMax(m2k + t * 64 + vm, __float_as_uint(v));  // soft > 0
    }
}

// ---------------------------------------------------------------------------
extern "C" void kernel_launch(void* const* d_in, const int* in_sizes, int n_in,
                              void* d_out, int out_size, void* d_ws, size_t ws_size,
                              hipStream_t stream) {
    const float* fuse = (const float*)d_in[0];
    const float* Wq   = (const float*)d_in[1];
    const float* bq   = (const float*)d_in[2];
    const float* Wk   = (const float*)d_in[3];
    const float* bk   = (const float*)d_in[4];
    const float* Wv   = (const float*)d_in[5];
    const float* bv   = (const float*)d_in[6];
    float* out = (float*)d_out;

    char* ws = (char*)d_ws;
    ushort* fT    = (ushort*)(ws);                       // 8 MiB
    ushort* Wq16  = (ushort*)(ws + 8388608);             // 128 KiB
    ushort* Wk16  = (ushort*)(ws + 8519680);             // 128 KiB
    ushort* Wv16  = (ushort*)(ws + 8650752);             // 128 KiB
    u8*     Qw8   = (u8*)    (ws + 8781824);             // 4 MiB (fp8 frag-major)
    u8*     Kw8   = (u8*)    (ws + 12976128);            // 4 MiB (fp8 frag-major)
    unsigned int* QMK = (unsigned int*)(ws + 17170432);  // 64 KiB (Q_mask keys)
    unsigned int* M2K = (unsigned int*)(ws + 17235968);  // 1 KiB (m2 keys)

    prep_kernel<<<256, 256, 0, stream>>>(Wq, Wk, Wv, Wq16, Wk16, Wv16, M2K, QMK);
    transpose_kernel<<<dim3(64, 8, NB), 256, 0, stream>>>(fuse, fT);
    conv_gemm_kernel<2><<<dim3(64, NB), 256, 0, stream>>>(   // Q + Q_mask
        fT, Wq16, bq, Qw8, nullptr, nullptr, nullptr, QMK);
    conv_gemm_kernel<0><<<dim3(64, NB), 256, 0, stream>>>(   // K
        fT, Wk16, bk, Kw8, nullptr, nullptr, nullptr, nullptr);
    scores64<<<4096, 256, 0, stream>>>(Qw8, Kw8, M2K);
    conv_gemm_kernel<1><<<dim3(64, NB), 256, 0, stream>>>(   // V + mask epilogue
        fT, Wv16, bv, nullptr, out, M2K, QMK, nullptr);
}

// Round 12
// 90.736 us; speedup vs baseline: 1.8906x; 1.2467x over previous
//
#include <hip/hip_runtime.h>
#include <stdint.h>

#define HW 4096
#define CH 256
#define NB 4

typedef __attribute__((ext_vector_type(8))) short bf16x8;
typedef __attribute__((ext_vector_type(4))) float f32x4;
typedef unsigned char u8;

__device__ __forceinline__ ushort f2bf(float f) {
    uint32_t u = __float_as_uint(f);
    u += 0x7fffu + ((u >> 16) & 1u);   // RNE
    return (ushort)(u >> 16);
}
// monotone float<->uint key (handles negatives) for atomicMax reductions
__device__ __forceinline__ uint fkey(float f) {
    uint b = __float_as_uint(f);
    return ((int)b < 0) ? ~b : (b | 0x80000000u);
}
__device__ __forceinline__ float finv(uint k) {
    uint b = (k & 0x80000000u) ? (k ^ 0x80000000u) : ~k;
    return __uint_as_float(b);
}

// ---------------------------------------------------------------------------
// prep: convert 3 weight matrices fp32->bf16, zero m2/Qmask key accumulators
__global__ __launch_bounds__(256) void prep_kernel(
    const float* __restrict__ Wq, const float* __restrict__ Wk,
    const float* __restrict__ Wv,
    ushort* __restrict__ Wq16, ushort* __restrict__ Wk16,
    ushort* __restrict__ Wv16, unsigned int* __restrict__ m2k,
    unsigned int* __restrict__ qmk) {
    int i = blockIdx.x * 256 + threadIdx.x;   // grid covers 65536
    Wq16[i] = f2bf(Wq[i]);
    Wk16[i] = f2bf(Wk[i]);
    Wv16[i] = f2bf(Wv[i]);
    if (i < NB * HW) qmk[i] = 0;              // fkey-min
    if (i < NB * 64) m2k[i] = 0;              // positive-float-min
}

// ---------------------------------------------------------------------------
// Fused Q+K conv1x1, reading fuse DIRECTLY (transposing LDS stage replaces
// the old standalone transpose kernel; conversion path f32->bf16 identical).
// Per kc: stage Wq,Wk rows + fuse tile 64c x 64hw f32 -> tileF; then
// tileF -> Bls bf16 transposed; MFMA both Q and K off the SAME Bls.
// Outputs: Qw8/Kw8 fp8 e4m3 16x16-fragment-major (R8-validated index) and
// Q_mask block-reduce from fp32 acc -> qmout (fkey atomicMax).
__global__ __launch_bounds__(256) void convQK_kernel(
    const float* __restrict__ fuse,
    const ushort* __restrict__ Wq16, const ushort* __restrict__ Wk16,
    const float* __restrict__ bq, const float* __restrict__ bk,
    u8* __restrict__ Qw8, u8* __restrict__ Kw8,
    unsigned int* __restrict__ qmout) {
    __shared__ __align__(16) ushort WqLs[256][72];
    __shared__ __align__(16) ushort WkLs[256][72];
    __shared__ __align__(16) float tileF[64][65];
    __shared__ __align__(16) ushort Bls[64][72];
    __shared__ float qred[4][4][64];
    const int t = threadIdx.x;
    const int lane = t & 63, w = t >> 6;
    const int hw0 = blockIdx.x * 64;
    const int b = blockIdx.y;
    f32x4 accQ[4][4] = {}, accK[4][4] = {};   // [rf(o)][cf(hw)]
    for (int kc = 0; kc < 4; ++kc) {
        __syncthreads();
        #pragma unroll
        for (int i = 0; i < 8; ++i) {
            int q = t + 256 * i;
            int row = q >> 3, c8 = (q & 7) * 8;
            *(int4*)&WqLs[row][c8] =
                *(const int4*)(Wq16 + (size_t)row * CH + kc * 64 + c8);
            *(int4*)&WkLs[row][c8] =
                *(const int4*)(Wk16 + (size_t)row * CH + kc * 64 + c8);
        }
        {   // stage fuse[b][kc*64 + c][hw0..64] -> tileF[c][hw] (coalesced)
            const int c = t >> 2, q4 = (t & 3) * 16;
            const float* src = fuse + ((size_t)b * CH + kc * 64 + c) * HW + hw0 + q4;
            #pragma unroll
            for (int q = 0; q < 4; ++q) {
                float4 v = *(const float4*)(src + q * 4);
                tileF[c][q4 + q * 4 + 0] = v.x; tileF[c][q4 + q * 4 + 1] = v.y;
                tileF[c][q4 + q * 4 + 2] = v.z; tileF[c][q4 + q * 4 + 3] = v.w;
            }
        }
        __syncthreads();
        #pragma unroll
        for (int rep = 0; rep < 2; ++rep) {   // tileF -> Bls[hw][c] bf16
            int u = t + rep * 256;
            int hw = u >> 3, i8 = (u & 7) * 8;
            __align__(16) ushort o8[8];
            #pragma unroll
            for (int k = 0; k < 8; ++k) o8[k] = f2bf(tileF[i8 + k][hw]);
            *(int4*)&Bls[hw][i8] = *(const int4*)o8;
        }
        __syncthreads();
        #pragma unroll
        for (int kk = 0; kk < 2; ++kk) {
            bf16x8 aq[4], ak[4];
            #pragma unroll
            for (int rf = 0; rf < 4; ++rf) {
                aq[rf] = *(const bf16x8*)&WqLs[w * 64 + rf * 16 + (lane & 15)]
                                              [kk * 32 + (lane >> 4) * 8];
                ak[rf] = *(const bf16x8*)&WkLs[w * 64 + rf * 16 + (lane & 15)]
                                              [kk * 32 + (lane >> 4) * 8];
            }
            #pragma unroll
            for (int cf = 0; cf < 4; ++cf) {
                bf16x8 bf_ = *(const bf16x8*)&Bls[cf * 16 + (lane & 15)]
                                                 [kk * 32 + (lane >> 4) * 8];
                #pragma unroll
                for (int rf = 0; rf < 4; ++rf) {
                    accQ[rf][cf] = __builtin_amdgcn_mfma_f32_16x16x32_bf16(
                        aq[rf], bf_, accQ[rf][cf], 0, 0, 0);
                    accK[rf][cf] = __builtin_amdgcn_mfma_f32_16x16x32_bf16(
                        ak[rf], bf_, accK[rf][cf], 0, 0, 0);
                }
            }
        }
    }
    float qmx[4][4];   // [cf][r] running max for Q_mask
    #pragma unroll
    for (int cf = 0; cf < 4; ++cf)
        #pragma unroll
        for (int r = 0; r < 4; ++r) qmx[cf][r] = -3.4e38f;
    #pragma unroll
    for (int rf = 0; rf < 4; ++rf) {
        const int ob = w * 64 + rf * 16 + (lane >> 4) * 4;  // o base (mult of 4)
        #pragma unroll
        for (int cf = 0; cf < 4; ++cf) {
            const int hw = hw0 + cf * 16 + (lane & 15);
            size_t idx = ((((size_t)b * 8 + (ob >> 5)) * 256 + (hw >> 4)) * 64
                          + ((ob >> 3) & 3) * 16 + (hw & 15)) * 8 + (ob & 7);
            {   // Q
                float v0 = accQ[rf][cf][0] + bq[ob + 0];
                float v1 = accQ[rf][cf][1] + bq[ob + 1];
                float v2 = accQ[rf][cf][2] + bq[ob + 2];
                float v3 = accQ[rf][cf][3] + bq[ob + 3];
                int u = __builtin_amdgcn_cvt_pk_fp8_f32(v0, v1, 0, false);
                u = __builtin_amdgcn_cvt_pk_fp8_f32(v2, v3, u, true);
                *(unsigned int*)&Qw8[idx] = (unsigned int)u;
                qmx[cf][0] = fmaxf(qmx[cf][0], v0);
                qmx[cf][1] = fmaxf(qmx[cf][1], v1);
                qmx[cf][2] = fmaxf(qmx[cf][2], v2);
                qmx[cf][3] = fmaxf(qmx[cf][3], v3);
            }
            {   // K
                float v0 = accK[rf][cf][0] + bk[ob + 0];
                float v1 = accK[rf][cf][1] + bk[ob + 1];
                float v2 = accK[rf][cf][2] + bk[ob + 2];
                float v3 = accK[rf][cf][3] + bk[ob + 3];
                int u = __builtin_amdgcn_cvt_pk_fp8_f32(v0, v1, 0, false);
                u = __builtin_amdgcn_cvt_pk_fp8_f32(v2, v3, u, true);
                *(unsigned int*)&Kw8[idx] = (unsigned int)u;
            }
        }
    }
    // Q_mask reduce: lanes l, l^16, l^32, l^48 share hw col & class r
    #pragma unroll
    for (int cf = 0; cf < 4; ++cf)
        #pragma unroll
        for (int r = 0; r < 4; ++r) {
            float v = qmx[cf][r];
            v = fmaxf(v, __shfl_xor(v, 16));
            v = fmaxf(v, __shfl_xor(v, 32));
            qmx[cf][r] = v;
        }
    __syncthreads();
    if (lane < 16) {
        #pragma unroll
        for (int cf = 0; cf < 4; ++cf)
            #pragma unroll
            for (int r = 0; r < 4; ++r)
                qred[w][r][cf * 16 + lane] = qmx[cf][r];
    }
    __syncthreads();
    {
        const int r = t >> 6, h64 = t & 63;
        float v = fmaxf(fmaxf(qred[0][r][h64], qred[1][r][h64]),
                        fmaxf(qred[2][r][h64], qred[3][r][h64]));
        atomicMax(qmout + r * HW + hw0 + h64, fkey(v));
    }
}

// ---------------------------------------------------------------------------
// V conv + mask epilogue, reading fuse directly (same transposing stage).
__global__ __launch_bounds__(256) void convV_kernel(
    const float* __restrict__ fuse, const ushort* __restrict__ Wv16,
    const float* __restrict__ bv, float* __restrict__ outf,
    const unsigned int* __restrict__ m2key,
    const unsigned int* __restrict__ qmkey) {
    __shared__ __align__(16) ushort Als[256][72];
    __shared__ __align__(16) float tileF[64][65];
    __shared__ __align__(16) ushort Bls[64][72];
    __shared__ float m2s[64];
    const int t = threadIdx.x;
    const int lane = t & 63, w = t >> 6;
    const int hw0 = blockIdx.x * 64;
    const int b = blockIdx.y;
    if (t < 64) m2s[t] = __uint_as_float(m2key[b * 64 + t]);
    f32x4 acc[4][4] = {};
    for (int kc = 0; kc < 4; ++kc) {
        __syncthreads();
        #pragma unroll
        for (int i = 0; i < 8; ++i) {
            int q = t + 256 * i;
            int row = q >> 3, c8 = (q & 7) * 8;
            *(int4*)&Als[row][c8] =
                *(const int4*)(Wv16 + (size_t)row * CH + kc * 64 + c8);
        }
        {
            const int c = t >> 2, q4 = (t & 3) * 16;
            const float* src = fuse + ((size_t)b * CH + kc * 64 + c) * HW + hw0 + q4;
            #pragma unroll
            for (int q = 0; q < 4; ++q) {
                float4 v = *(const float4*)(src + q * 4);
                tileF[c][q4 + q * 4 + 0] = v.x; tileF[c][q4 + q * 4 + 1] = v.y;
                tileF[c][q4 + q * 4 + 2] = v.z; tileF[c][q4 + q * 4 + 3] = v.w;
            }
        }
        __syncthreads();
        #pragma unroll
        for (int rep = 0; rep < 2; ++rep) {
            int u = t + rep * 256;
            int hw = u >> 3, i8 = (u & 7) * 8;
            __align__(16) ushort o8[8];
            #pragma unroll
            for (int k = 0; k < 8; ++k) o8[k] = f2bf(tileF[i8 + k][hw]);
            *(int4*)&Bls[hw][i8] = *(const int4*)o8;
        }
        __syncthreads();
        #pragma unroll
        for (int kk = 0; kk < 2; ++kk) {
            bf16x8 af[4];
            #pragma unroll
            for (int rf = 0; rf < 4; ++rf)
                af[rf] = *(const bf16x8*)&Als[w * 64 + rf * 16 + (lane & 15)]
                                             [kk * 32 + (lane >> 4) * 8];
            #pragma unroll
            for (int cf = 0; cf < 4; ++cf) {
                bf16x8 bf_ = *(const bf16x8*)&Bls[cf * 16 + (lane & 15)]
                                                 [kk * 32 + (lane >> 4) * 8];
                #pragma unroll
                for (int rf = 0; rf < 4; ++rf)
                    acc[rf][cf] = __builtin_amdgcn_mfma_f32_16x16x32_bf16(
                        af[rf], bf_, acc[rf][cf], 0, 0, 0);
            }
        }
    }
    #pragma unroll
    for (int rf = 0; rf < 4; ++rf) {
        const int ob = w * 64 + rf * 16 + (lane >> 4) * 4;
        #pragma unroll
        for (int cf = 0; cf < 4; ++cf) {
            const int hw = hw0 + cf * 16 + (lane & 15);
            const float mv = m2s[ob >> 2];
            #pragma unroll
            for (int r = 0; r < 4; ++r) {   // o = ob+r, o%4 == r
                float vv = acc[rf][cf][r] + bv[ob + r];
                float qm = finv(qmkey[r * HW + hw]);
                outf[((size_t)b * CH + ob + r) * HW + hw] = vv * (1.0f + mv * qm);
            }
        }
    }
}

// ---------------------------------------------------------------------------
// scores64 (8-wave): 64n x 64m tile per 512-thread block. Wave w = (batch
// b = w&3, m-half mh = w>>2): acc[4 nf][2 mf] = 32 regs/wave -> ~6 waves/SIMD
// resident (the R10/R11 structure was TLP-starved at 3: load-wait ~550 cyc
// vs 2x315 cyc of MFMA cover). K-loop: fp8 fragments global->VGPR, no
// barriers. Epilogue: EX exchange (8 waves fill 16 [b][mf] slots, 2 each),
// read side splits jj halves across wave-halves; 4 atomics/block (m2 only).
__global__ __launch_bounds__(512, 4) void scores64(
    const u8* __restrict__ Qw, const u8* __restrict__ Kw,
    unsigned int* __restrict__ m2k) {
    __shared__ __align__(16) f32x4 EX[4][4][64];   // [b][mf][lane] 16 KB
    __shared__ float red[8][4];                    // [wave][batch]
    const int t = threadIdx.x;
    const int lane = t & 63, w = t >> 6;           // 8 waves
    const int b = w & 3, mh = w >> 2;
    // XCD-rectangle swizzle: xcd gets 16n x 32m tiles (Q 1MB + K 2MB < 4MB L2)
    const int bid = blockIdx.x;
    const int xcd = bid & 7, j = bid >> 3;
    const int vn = (xcd & 3) * 16 + (j & 15);
    const int vm = (xcd >> 2) * 32 + (j >> 4);

    const u8* qp = Qw + (((size_t)b * 8) * 256 + vn * 4) * 512 + lane * 8;
    const u8* kp = Kw + (((size_t)b * 8) * 256 + vm * 4 + mh * 2) * 512 + lane * 8;

    f32x4 acc[4][2] = {};   // [nf][mf-within-half]
    #pragma unroll
    for (int kc = 0; kc < 8; ++kc) {
        long af[4], bf[2];
        #pragma unroll
        for (int nf = 0; nf < 4; ++nf)
            af[nf] = *(const long*)(qp + (size_t)kc * 131072 + nf * 512);
        #pragma unroll
        for (int mf = 0; mf < 2; ++mf)
            bf[mf] = *(const long*)(kp + (size_t)kc * 131072 + mf * 512);
        #pragma unroll
        for (int mf = 0; mf < 2; ++mf)
            #pragma unroll
            for (int nf = 0; nf < 4; ++nf)
                acc[nf][mf] = __builtin_amdgcn_mfma_f32_16x16x32_fp8_fp8(
                    af[nf], bf[mf], acc[nf][mf], 0, 0, 0);
    }

    // ---- exchange + softmax: 4 substeps over nf ----
    const int mfo = w & 3, jh = w >> 2;   // read-side ownership
    float pmAll[4] = {0.f, 0.f, 0.f, 0.f};
    #pragma unroll
    for (int nf = 0; nf < 4; ++nf) {
        if (nf) __syncthreads();          // previous substep's reads done
        #pragma unroll
        for (int mf = 0; mf < 2; ++mf)
            EX[b][mh * 2 + mf][lane] = acc[nf][mf];
        __syncthreads();
        f32x4 sv[4];
        #pragma unroll
        for (int b2 = 0; b2 < 4; ++b2)
            sv[b2] = EX[b2][mfo][lane];
        #pragma unroll
        for (int jq = 0; jq < 2; ++jq) {
            const int jj = jh * 2 + jq;
            float e0 = __expf(sv[0][jj] * 0.0625f);
            float e1 = __expf(sv[1][jj] * 0.0625f);
            float e2 = __expf(sv[2][jj] * 0.0625f);
            float e3 = __expf(sv[3][jj] * 0.0625f);
            float inv = __fdividef(1.0f, e0 + e1 + e2 + e3);
            pmAll[0] = fmaxf(pmAll[0], e0 * inv);
            pmAll[1] = fmaxf(pmAll[1], e1 * inv);
            pmAll[2] = fmaxf(pmAll[2], e2 * inv);
            pmAll[3] = fmaxf(pmAll[3], e3 * inv);
        }
    }
    // wave reduce (max over all lanes), then block reduce, 4 atomics
    #pragma unroll
    for (int off = 32; off >= 1; off >>= 1) {
        pmAll[0] = fmaxf(pmAll[0], __shfl_xor(pmAll[0], off));
        pmAll[1] = fmaxf(pmAll[1], __shfl_xor(pmAll[1], off));
        pmAll[2] = fmaxf(pmAll[2], __shfl_xor(pmAll[2], off));
        pmAll[3] = fmaxf(pmAll[3], __shfl_xor(pmAll[3], off));
    }
    __syncthreads();   // EX reads done; red aliases fresh region anyway
    if (lane == 0) {
        #pragma unroll
        for (int b2 = 0; b2 < 4; ++b2) red[w][b2] = pmAll[b2];
    }
    __syncthreads();
    if (t < 4) {   // t = batch
        float v = red[0][t];
        #pragma unroll
        for (int w2 = 1; w2 < 8; ++w2) v = fmaxf(v, red[w2][t]);
        atomicMax(m2k + t * 64 + vm, __float_as_uint(v));  // soft > 0
    }
}

// ---------------------------------------------------------------------------
extern "C" void kernel_launch(void* const* d_in, const int* in_sizes, int n_in,
                              void* d_out, int out_size, void* d_ws, size_t ws_size,
                              hipStream_t stream) {
    const float* fuse = (const float*)d_in[0];
    const float* Wq   = (const float*)d_in[1];
    const float* bq   = (const float*)d_in[2];
    const float* Wk   = (const float*)d_in[3];
    const float* bk   = (const float*)d_in[4];
    const float* Wv   = (const float*)d_in[5];
    const float* bv   = (const float*)d_in[6];
    float* out = (float*)d_out;

    char* ws = (char*)d_ws;
    ushort* Wq16  = (ushort*)(ws);                      // 128 KiB
    ushort* Wk16  = (ushort*)(ws + 131072);             // 128 KiB
    ushort* Wv16  = (ushort*)(ws + 262144);             // 128 KiB
    u8*     Qw8   = (u8*)    (ws + 393216);             // 4 MiB (fp8 frag-major)
    u8*     Kw8   = (u8*)    (ws + 4587520);            // 4 MiB (fp8 frag-major)
    unsigned int* QMK = (unsigned int*)(ws + 8781824);  // 64 KiB (Q_mask keys)
    unsigned int* M2K = (unsigned int*)(ws + 8847360);  // 1 KiB (m2 keys)

    prep_kernel<<<256, 256, 0, stream>>>(Wq, Wk, Wv, Wq16, Wk16, Wv16, M2K, QMK);
    convQK_kernel<<<dim3(64, NB), 256, 0, stream>>>(
        fuse, Wq16, Wk16, bq, bk, Qw8, Kw8, QMK);
    scores64<<<4096, 512, 0, stream>>>(Qw8, Kw8, M2K);
    convV_kernel<<<dim3(64, NB), 256, 0, stream>>>(
        fuse, Wv16, bv, out, M2K, QMK);
}

// Round 13
// 77.927 us; speedup vs baseline: 2.2013x; 1.1644x over previous
//
#include <hip/hip_runtime.h>
#include <stdint.h>

#define HW 4096
#define CH 256
#define NB 4

typedef __attribute__((ext_vector_type(8))) short bf16x8;
typedef __attribute__((ext_vector_type(4))) float f32x4;
typedef __attribute__((ext_vector_type(2))) long longx2;
typedef unsigned char u8;

__device__ __forceinline__ ushort f2bf(float f) {
    uint32_t u = __float_as_uint(f);
    u += 0x7fffu + ((u >> 16) & 1u);   // RNE
    return (ushort)(u >> 16);
}
// monotone float<->uint key (handles negatives) for atomicMax reductions
__device__ __forceinline__ uint fkey(float f) {
    uint b = __float_as_uint(f);
    return ((int)b < 0) ? ~b : (b | 0x80000000u);
}
__device__ __forceinline__ float finv(uint k) {
    uint b = (k & 0x80000000u) ? (k ^ 0x80000000u) : ~k;
    return __uint_as_float(b);
}

// fp8 fragment-PAIR index: fragments for adjacent 16-hw blocks are
// interleaved per-lane (lane's 16B = 8B of even frag || 8B of odd frag),
// so ONE dwordx4 wave-load feeds TWO MFMA operands.
__device__ __forceinline__ size_t fragidx(int b, int o, int hw) {
    return ((((size_t)b * 8 + (o >> 5)) * 128 + (hw >> 5)) * 1024)
         + ((((o >> 3) & 3) * 16 + (hw & 15)) * 16)
         + (((hw >> 4) & 1) * 8) + (o & 7);
}

// ---------------------------------------------------------------------------
// prep: convert 3 weight matrices fp32->bf16, zero m2/Qmask key accumulators
__global__ __launch_bounds__(256) void prep_kernel(
    const float* __restrict__ Wq, const float* __restrict__ Wk,
    const float* __restrict__ Wv,
    ushort* __restrict__ Wq16, ushort* __restrict__ Wk16,
    ushort* __restrict__ Wv16, unsigned int* __restrict__ m2k,
    unsigned int* __restrict__ qmk) {
    int i = blockIdx.x * 256 + threadIdx.x;   // grid covers 65536
    Wq16[i] = f2bf(Wq[i]);
    Wk16[i] = f2bf(Wk[i]);
    Wv16[i] = f2bf(Wv[i]);
    if (i < NB * HW) qmk[i] = 0;              // fkey-min
    if (i < NB * 64) m2k[i] = 0;              // positive-float-min
}

// ---------------------------------------------------------------------------
// Fused Q+K conv1x1, reading fuse DIRECTLY (transposing LDS stage).
// Outputs: Qw8/Kw8 fp8 e4m3 pair-packed fragment-major + Q_mask reduce.
__global__ __launch_bounds__(256) void convQK_kernel(
    const float* __restrict__ fuse,
    const ushort* __restrict__ Wq16, const ushort* __restrict__ Wk16,
    const float* __restrict__ bq, const float* __restrict__ bk,
    u8* __restrict__ Qw8, u8* __restrict__ Kw8,
    unsigned int* __restrict__ qmout) {
    __shared__ __align__(16) ushort WqLs[256][72];
    __shared__ __align__(16) ushort WkLs[256][72];
    __shared__ __align__(16) float tileF[64][65];
    __shared__ __align__(16) ushort Bls[64][72];
    __shared__ float qred[4][4][64];
    const int t = threadIdx.x;
    const int lane = t & 63, w = t >> 6;
    const int hw0 = blockIdx.x * 64;
    const int b = blockIdx.y;
    f32x4 accQ[4][4] = {}, accK[4][4] = {};   // [rf(o)][cf(hw)]
    for (int kc = 0; kc < 4; ++kc) {
        __syncthreads();
        #pragma unroll
        for (int i = 0; i < 8; ++i) {
            int q = t + 256 * i;
            int row = q >> 3, c8 = (q & 7) * 8;
            *(int4*)&WqLs[row][c8] =
                *(const int4*)(Wq16 + (size_t)row * CH + kc * 64 + c8);
            *(int4*)&WkLs[row][c8] =
                *(const int4*)(Wk16 + (size_t)row * CH + kc * 64 + c8);
        }
        {   // stage fuse[b][kc*64 + c][hw0..64] -> tileF[c][hw] (coalesced)
            const int c = t >> 2, q4 = (t & 3) * 16;
            const float* src = fuse + ((size_t)b * CH + kc * 64 + c) * HW + hw0 + q4;
            #pragma unroll
            for (int q = 0; q < 4; ++q) {
                float4 v = *(const float4*)(src + q * 4);
                tileF[c][q4 + q * 4 + 0] = v.x; tileF[c][q4 + q * 4 + 1] = v.y;
                tileF[c][q4 + q * 4 + 2] = v.z; tileF[c][q4 + q * 4 + 3] = v.w;
            }
        }
        __syncthreads();
        #pragma unroll
        for (int rep = 0; rep < 2; ++rep) {   // tileF -> Bls[hw][c] bf16
            int u = t + rep * 256;
            int hw = u >> 3, i8 = (u & 7) * 8;
            __align__(16) ushort o8[8];
            #pragma unroll
            for (int k = 0; k < 8; ++k) o8[k] = f2bf(tileF[i8 + k][hw]);
            *(int4*)&Bls[hw][i8] = *(const int4*)o8;
        }
        __syncthreads();
        #pragma unroll
        for (int kk = 0; kk < 2; ++kk) {
            bf16x8 aq[4], ak[4];
            #pragma unroll
            for (int rf = 0; rf < 4; ++rf) {
                aq[rf] = *(const bf16x8*)&WqLs[w * 64 + rf * 16 + (lane & 15)]
                                              [kk * 32 + (lane >> 4) * 8];
                ak[rf] = *(const bf16x8*)&WkLs[w * 64 + rf * 16 + (lane & 15)]
                                              [kk * 32 + (lane >> 4) * 8];
            }
            #pragma unroll
            for (int cf = 0; cf < 4; ++cf) {
                bf16x8 bf_ = *(const bf16x8*)&Bls[cf * 16 + (lane & 15)]
                                                 [kk * 32 + (lane >> 4) * 8];
                #pragma unroll
                for (int rf = 0; rf < 4; ++rf) {
                    accQ[rf][cf] = __builtin_amdgcn_mfma_f32_16x16x32_bf16(
                        aq[rf], bf_, accQ[rf][cf], 0, 0, 0);
                    accK[rf][cf] = __builtin_amdgcn_mfma_f32_16x16x32_bf16(
                        ak[rf], bf_, accK[rf][cf], 0, 0, 0);
                }
            }
        }
    }
    float qmx[4][4];   // [cf][r] running max for Q_mask
    #pragma unroll
    for (int cf = 0; cf < 4; ++cf)
        #pragma unroll
        for (int r = 0; r < 4; ++r) qmx[cf][r] = -3.4e38f;
    #pragma unroll
    for (int rf = 0; rf < 4; ++rf) {
        const int ob = w * 64 + rf * 16 + (lane >> 4) * 4;  // o base (mult of 4)
        #pragma unroll
        for (int cf = 0; cf < 4; ++cf) {
            const int hw = hw0 + cf * 16 + (lane & 15);
            size_t idx = fragidx(b, ob, hw);
            {   // Q
                float v0 = accQ[rf][cf][0] + bq[ob + 0];
                float v1 = accQ[rf][cf][1] + bq[ob + 1];
                float v2 = accQ[rf][cf][2] + bq[ob + 2];
                float v3 = accQ[rf][cf][3] + bq[ob + 3];
                int u = __builtin_amdgcn_cvt_pk_fp8_f32(v0, v1, 0, false);
                u = __builtin_amdgcn_cvt_pk_fp8_f32(v2, v3, u, true);
                *(unsigned int*)&Qw8[idx] = (unsigned int)u;
                qmx[cf][0] = fmaxf(qmx[cf][0], v0);
                qmx[cf][1] = fmaxf(qmx[cf][1], v1);
                qmx[cf][2] = fmaxf(qmx[cf][2], v2);
                qmx[cf][3] = fmaxf(qmx[cf][3], v3);
            }
            {   // K
                float v0 = accK[rf][cf][0] + bk[ob + 0];
                float v1 = accK[rf][cf][1] + bk[ob + 1];
                float v2 = accK[rf][cf][2] + bk[ob + 2];
                float v3 = accK[rf][cf][3] + bk[ob + 3];
                int u = __builtin_amdgcn_cvt_pk_fp8_f32(v0, v1, 0, false);
                u = __builtin_amdgcn_cvt_pk_fp8_f32(v2, v3, u, true);
                *(unsigned int*)&Kw8[idx] = (unsigned int)u;
            }
        }
    }
    // Q_mask reduce: lanes l, l^16, l^32, l^48 share hw col & class r
    #pragma unroll
    for (int cf = 0; cf < 4; ++cf)
        #pragma unroll
        for (int r = 0; r < 4; ++r) {
            float v = qmx[cf][r];
            v = fmaxf(v, __shfl_xor(v, 16));
            v = fmaxf(v, __shfl_xor(v, 32));
            qmx[cf][r] = v;
        }
    __syncthreads();
    if (lane < 16) {
        #pragma unroll
        for (int cf = 0; cf < 4; ++cf)
            #pragma unroll
            for (int r = 0; r < 4; ++r)
                qred[w][r][cf * 16 + lane] = qmx[cf][r];
    }
    __syncthreads();
    {
        const int r = t >> 6, h64 = t & 63;
        float v = fmaxf(fmaxf(qred[0][r][h64], qred[1][r][h64]),
                        fmaxf(qred[2][r][h64], qred[3][r][h64]));
        atomicMax(qmout + r * HW + hw0 + h64, fkey(v));
    }
}

// ---------------------------------------------------------------------------
// V conv + mask epilogue, reading fuse directly (same transposing stage).
__global__ __launch_bounds__(256) void convV_kernel(
    const float* __restrict__ fuse, const ushort* __restrict__ Wv16,
    const float* __restrict__ bv, float* __restrict__ outf,
    const unsigned int* __restrict__ m2key,
    const unsigned int* __restrict__ qmkey) {
    __shared__ __align__(16) ushort Als[256][72];
    __shared__ __align__(16) float tileF[64][65];
    __shared__ __align__(16) ushort Bls[64][72];
    __shared__ float m2s[64];
    const int t = threadIdx.x;
    const int lane = t & 63, w = t >> 6;
    const int hw0 = blockIdx.x * 64;
    const int b = blockIdx.y;
    if (t < 64) m2s[t] = __uint_as_float(m2key[b * 64 + t]);
    f32x4 acc[4][4] = {};
    for (int kc = 0; kc < 4; ++kc) {
        __syncthreads();
        #pragma unroll
        for (int i = 0; i < 8; ++i) {
            int q = t + 256 * i;
            int row = q >> 3, c8 = (q & 7) * 8;
            *(int4*)&Als[row][c8] =
                *(const int4*)(Wv16 + (size_t)row * CH + kc * 64 + c8);
        }
        {
            const int c = t >> 2, q4 = (t & 3) * 16;
            const float* src = fuse + ((size_t)b * CH + kc * 64 + c) * HW + hw0 + q4;
            #pragma unroll
            for (int q = 0; q < 4; ++q) {
                float4 v = *(const float4*)(src + q * 4);
                tileF[c][q4 + q * 4 + 0] = v.x; tileF[c][q4 + q * 4 + 1] = v.y;
                tileF[c][q4 + q * 4 + 2] = v.z; tileF[c][q4 + q * 4 + 3] = v.w;
            }
        }
        __syncthreads();
        #pragma unroll
        for (int rep = 0; rep < 2; ++rep) {
            int u = t + rep * 256;
            int hw = u >> 3, i8 = (u & 7) * 8;
            __align__(16) ushort o8[8];
            #pragma unroll
            for (int k = 0; k < 8; ++k) o8[k] = f2bf(tileF[i8 + k][hw]);
            *(int4*)&Bls[hw][i8] = *(const int4*)o8;
        }
        __syncthreads();
        #pragma unroll
        for (int kk = 0; kk < 2; ++kk) {
            bf16x8 af[4];
            #pragma unroll
            for (int rf = 0; rf < 4; ++rf)
                af[rf] = *(const bf16x8*)&Als[w * 64 + rf * 16 + (lane & 15)]
                                             [kk * 32 + (lane >> 4) * 8];
            #pragma unroll
            for (int cf = 0; cf < 4; ++cf) {
                bf16x8 bf_ = *(const bf16x8*)&Bls[cf * 16 + (lane & 15)]
                                                 [kk * 32 + (lane >> 4) * 8];
                #pragma unroll
                for (int rf = 0; rf < 4; ++rf)
                    acc[rf][cf] = __builtin_amdgcn_mfma_f32_16x16x32_bf16(
                        af[rf], bf_, acc[rf][cf], 0, 0, 0);
            }
        }
    }
    #pragma unroll
    for (int rf = 0; rf < 4; ++rf) {
        const int ob = w * 64 + rf * 16 + (lane >> 4) * 4;
        #pragma unroll
        for (int cf = 0; cf < 4; ++cf) {
            const int hw = hw0 + cf * 16 + (lane & 15);
            const float mv = m2s[ob >> 2];
            #pragma unroll
            for (int r = 0; r < 4; ++r) {   // o = ob+r, o%4 == r
                float vv = acc[rf][cf][r] + bv[ob + r];
                float qm = finv(qmkey[r * HW + hw]);
                outf[((size_t)b * CH + ob + r) * HW + hw] = vv * (1.0f + mv * qm);
            }
        }
    }
}

// ---------------------------------------------------------------------------
// scores64 (R10 4-wave structure + pair-packed loads): 64n x 64m tile per
// 256-thread block; wave w = batch w. K-loop: 4 dwordx4 loads/kc (each
// feeds TWO fp8 MFMA operands) -> half the load-dependency chains of R10,
// same bytes. No barriers in k-loop. Epilogue: EX exchange, each softmax
// item computed once, 4 atomics/block (m2 only).
__global__ __launch_bounds__(256) void scores64(
    const u8* __restrict__ Qw, const u8* __restrict__ Kw,
    unsigned int* __restrict__ m2k) {
    __shared__ __align__(16) f32x4 EX[4][4][64];   // [b][mf][lane] 16 KB
    __shared__ float red[4][4];                    // [wave][batch]
    const int t = threadIdx.x;
    const int lane = t & 63, w = t >> 6;           // w = batch
    // XCD-rectangle swizzle: xcd gets 16n x 32m tiles (Q 1MB + K 2MB < 4MB L2)
    const int bid = blockIdx.x;
    const int xcd = bid & 7, j = bid >> 3;
    const int vn = (xcd & 3) * 16 + (j & 15);
    const int vm = (xcd >> 2) * 32 + (j >> 4);

    // pair-region bases: pair (b, kc, pairblk) is 1KB; tile has 2 pairs
    const u8* qp = Qw + (((size_t)w * 8) * 128 + vn * 2) * 1024 + lane * 16;
    const u8* kp = Kw + (((size_t)w * 8) * 128 + vm * 2) * 1024 + lane * 16;

    f32x4 acc[4][4] = {};   // [nf][mf]
    #pragma unroll
    for (int kc = 0; kc < 8; ++kc) {
        longx2 aq[2], bk[2];
        #pragma unroll
        for (int p = 0; p < 2; ++p) {
            aq[p] = *(const longx2*)(qp + (size_t)kc * 131072 + p * 1024);
            bk[p] = *(const longx2*)(kp + (size_t)kc * 131072 + p * 1024);
        }
        #pragma unroll
        for (int mf = 0; mf < 4; ++mf) {
            long bf_ = bk[mf >> 1][mf & 1];
            #pragma unroll
            for (int nf = 0; nf < 4; ++nf)
                acc[nf][mf] = __builtin_amdgcn_mfma_f32_16x16x32_fp8_fp8(
                    aq[nf >> 1][nf & 1], bf_, acc[nf][mf], 0, 0, 0);
        }
    }

    // ---- exchange + softmax: 4 substeps over nf ----
    float pmAll[4] = {0.f, 0.f, 0.f, 0.f};
    #pragma unroll
    for (int nf = 0; nf < 4; ++nf) {
        if (nf) __syncthreads();          // previous substep's reads done
        #pragma unroll
        for (int mf = 0; mf < 4; ++mf)
            EX[w][mf][lane] = acc[nf][mf];
        __syncthreads();
        f32x4 sv[4];
        #pragma unroll
        for (int b2 = 0; b2 < 4; ++b2)
            sv[b2] = EX[b2][w][lane];     // this thread owns mf = w
        #pragma unroll
        for (int jj = 0; jj < 4; ++jj) {
            float e0 = __expf(sv[0][jj] * 0.0625f);
            float e1 = __expf(sv[1][jj] * 0.0625f);
            float e2 = __expf(sv[2][jj] * 0.0625f);
            float e3 = __expf(sv[3][jj] * 0.0625f);
            float inv = __fdividef(1.0f, e0 + e1 + e2 + e3);
            pmAll[0] = fmaxf(pmAll[0], e0 * inv);
            pmAll[1] = fmaxf(pmAll[1], e1 * inv);
            pmAll[2] = fmaxf(pmAll[2], e2 * inv);
            pmAll[3] = fmaxf(pmAll[3], e3 * inv);
        }
    }
    // wave reduce (max over all lanes), then block reduce, 4 atomics
    #pragma unroll
    for (int off = 32; off >= 1; off >>= 1) {
        pmAll[0] = fmaxf(pmAll[0], __shfl_xor(pmAll[0], off));
        pmAll[1] = fmaxf(pmAll[1], __shfl_xor(pmAll[1], off));
        pmAll[2] = fmaxf(pmAll[2], __shfl_xor(pmAll[2], off));
        pmAll[3] = fmaxf(pmAll[3], __shfl_xor(pmAll[3], off));
    }
    __syncthreads();   // EX reads done; red aliases fresh region anyway
    if (lane == 0) {
        #pragma unroll
        for (int b2 = 0; b2 < 4; ++b2) red[w][b2] = pmAll[b2];
    }
    __syncthreads();
    if (t < 4) {   // t = batch
        float v = fmaxf(fmaxf(red[0][t], red[1][t]),
                        fmaxf(red[2][t], red[3][t]));
        atomicMax(m2k + t * 64 + vm, __float_as_uint(v));  // soft > 0
    }
}

// ---------------------------------------------------------------------------
extern "C" void kernel_launch(void* const* d_in, const int* in_sizes, int n_in,
                              void* d_out, int out_size, void* d_ws, size_t ws_size,
                              hipStream_t stream) {
    const float* fuse = (const float*)d_in[0];
    const float* Wq   = (const float*)d_in[1];
    const float* bq   = (const float*)d_in[2];
    const float* Wk   = (const float*)d_in[3];
    const float* bk   = (const float*)d_in[4];
    const float* Wv   = (const float*)d_in[5];
    const float* bv   = (const float*)d_in[6];
    float* out = (float*)d_out;

    char* ws = (char*)d_ws;
    ushort* Wq16  = (ushort*)(ws);                      // 128 KiB
    ushort* Wk16  = (ushort*)(ws + 131072);             // 128 KiB
    ushort* Wv16  = (ushort*)(ws + 262144);             // 128 KiB
    u8*     Qw8   = (u8*)    (ws + 393216);             // 4 MiB (fp8 pair-frag)
    u8*     Kw8   = (u8*)    (ws + 4587520);            // 4 MiB (fp8 pair-frag)
    unsigned int* QMK = (unsigned int*)(ws + 8781824);  // 64 KiB (Q_mask keys)
    unsigned int* M2K = (unsigned int*)(ws + 8847360);  // 1 KiB (m2 keys)

    prep_kernel<<<256, 256, 0, stream>>>(Wq, Wk, Wv, Wq16, Wk16, Wv16, M2K, QMK);
    convQK_kernel<<<dim3(64, NB), 256, 0, stream>>>(
        fuse, Wq16, Wk16, bq, bk, Qw8, Kw8, QMK);
    scores64<<<4096, 256, 0, stream>>>(Qw8, Kw8, M2K);
    convV_kernel<<<dim3(64, NB), 256, 0, stream>>>(
        fuse, Wv16, bv, out, M2K, QMK);
}

// Round 14
// 74.492 us; speedup vs baseline: 2.3028x; 1.0461x over previous
//
#include <hip/hip_runtime.h>
#include <stdint.h>

#define HW 4096
#define CH 256
#define NB 4

typedef __attribute__((ext_vector_type(8))) short bf16x8;
typedef __attribute__((ext_vector_type(4))) float f32x4;
typedef __attribute__((ext_vector_type(2))) long longx2;
typedef unsigned char u8;

__device__ __forceinline__ ushort f2bf(float f) {
    uint32_t u = __float_as_uint(f);
    u += 0x7fffu + ((u >> 16) & 1u);   // RNE
    return (ushort)(u >> 16);
}
// monotone float<->uint key (handles negatives) for atomicMax reductions
__device__ __forceinline__ uint fkey(float f) {
    uint b = __float_as_uint(f);
    return ((int)b < 0) ? ~b : (b | 0x80000000u);
}
__device__ __forceinline__ float finv(uint k) {
    uint b = (k & 0x80000000u) ? (k ^ 0x80000000u) : ~k;
    return __uint_as_float(b);
}

// fp8 fragment-PAIR index: fragments for adjacent 16-hw blocks are
// interleaved per-lane (lane's 16B = 8B of even frag || 8B of odd frag),
// so ONE dwordx4 wave-load feeds TWO MFMA operands.
__device__ __forceinline__ size_t fragidx(int b, int o, int hw) {
    return ((((size_t)b * 8 + (o >> 5)) * 128 + (hw >> 5)) * 1024)
         + ((((o >> 3) & 3) * 16 + (hw & 15)) * 16)
         + (((hw >> 4) & 1) * 8) + (o & 7);
}

// ---------------------------------------------------------------------------
// prep: convert 3 weight matrices fp32->bf16, zero m2/Qmask key accumulators
__global__ __launch_bounds__(256) void prep_kernel(
    const float* __restrict__ Wq, const float* __restrict__ Wk,
    const float* __restrict__ Wv,
    ushort* __restrict__ Wq16, ushort* __restrict__ Wk16,
    ushort* __restrict__ Wv16, unsigned int* __restrict__ m2k,
    unsigned int* __restrict__ qmk) {
    int i = blockIdx.x * 256 + threadIdx.x;   // grid covers 65536
    Wq16[i] = f2bf(Wq[i]);
    Wk16[i] = f2bf(Wk[i]);
    Wv16[i] = f2bf(Wv[i]);
    if (i < NB * HW) qmk[i] = 0;              // fkey-min
    if (i < NB * 64) m2k[i] = 0;              // positive-float-min
}

// ---------------------------------------------------------------------------
// Fused Q+K conv1x1, reading fuse DIRECTLY (transposing LDS stage).
// Outputs: Qw8/Kw8 fp8 e4m3 pair-packed fragment-major + Q_mask reduce.
__global__ __launch_bounds__(256) void convQK_kernel(
    const float* __restrict__ fuse,
    const ushort* __restrict__ Wq16, const ushort* __restrict__ Wk16,
    const float* __restrict__ bq, const float* __restrict__ bk,
    u8* __restrict__ Qw8, u8* __restrict__ Kw8,
    unsigned int* __restrict__ qmout) {
    __shared__ __align__(16) ushort WqLs[256][72];
    __shared__ __align__(16) ushort WkLs[256][72];
    __shared__ __align__(16) float tileF[64][65];
    __shared__ __align__(16) ushort Bls[64][72];
    __shared__ float qred[4][4][64];
    const int t = threadIdx.x;
    const int lane = t & 63, w = t >> 6;
    const int hw0 = blockIdx.x * 64;
    const int b = blockIdx.y;
    f32x4 accQ[4][4] = {}, accK[4][4] = {};   // [rf(o)][cf(hw)]
    for (int kc = 0; kc < 4; ++kc) {
        __syncthreads();
        #pragma unroll
        for (int i = 0; i < 8; ++i) {
            int q = t + 256 * i;
            int row = q >> 3, c8 = (q & 7) * 8;
            *(int4*)&WqLs[row][c8] =
                *(const int4*)(Wq16 + (size_t)row * CH + kc * 64 + c8);
            *(int4*)&WkLs[row][c8] =
                *(const int4*)(Wk16 + (size_t)row * CH + kc * 64 + c8);
        }
        {   // stage fuse[b][kc*64 + c][hw0..64] -> tileF[c][hw] (coalesced)
            const int c = t >> 2, q4 = (t & 3) * 16;
            const float* src = fuse + ((size_t)b * CH + kc * 64 + c) * HW + hw0 + q4;
            #pragma unroll
            for (int q = 0; q < 4; ++q) {
                float4 v = *(const float4*)(src + q * 4);
                tileF[c][q4 + q * 4 + 0] = v.x; tileF[c][q4 + q * 4 + 1] = v.y;
                tileF[c][q4 + q * 4 + 2] = v.z; tileF[c][q4 + q * 4 + 3] = v.w;
            }
        }
        __syncthreads();
        #pragma unroll
        for (int rep = 0; rep < 2; ++rep) {   // tileF -> Bls[hw][c] bf16
            int u = t + rep * 256;
            int hw = u >> 3, i8 = (u & 7) * 8;
            __align__(16) ushort o8[8];
            #pragma unroll
            for (int k = 0; k < 8; ++k) o8[k] = f2bf(tileF[i8 + k][hw]);
            *(int4*)&Bls[hw][i8] = *(const int4*)o8;
        }
        __syncthreads();
        #pragma unroll
        for (int kk = 0; kk < 2; ++kk) {
            bf16x8 aq[4], ak[4];
            #pragma unroll
            for (int rf = 0; rf < 4; ++rf) {
                aq[rf] = *(const bf16x8*)&WqLs[w * 64 + rf * 16 + (lane & 15)]
                                              [kk * 32 + (lane >> 4) * 8];
                ak[rf] = *(const bf16x8*)&WkLs[w * 64 + rf * 16 + (lane & 15)]
                                              [kk * 32 + (lane >> 4) * 8];
            }
            #pragma unroll
            for (int cf = 0; cf < 4; ++cf) {
                bf16x8 bf_ = *(const bf16x8*)&Bls[cf * 16 + (lane & 15)]
                                                 [kk * 32 + (lane >> 4) * 8];
                #pragma unroll
                for (int rf = 0; rf < 4; ++rf) {
                    accQ[rf][cf] = __builtin_amdgcn_mfma_f32_16x16x32_bf16(
                        aq[rf], bf_, accQ[rf][cf], 0, 0, 0);
                    accK[rf][cf] = __builtin_amdgcn_mfma_f32_16x16x32_bf16(
                        ak[rf], bf_, accK[rf][cf], 0, 0, 0);
                }
            }
        }
    }
    float qmx[4][4];   // [cf][r] running max for Q_mask
    #pragma unroll
    for (int cf = 0; cf < 4; ++cf)
        #pragma unroll
        for (int r = 0; r < 4; ++r) qmx[cf][r] = -3.4e38f;
    #pragma unroll
    for (int rf = 0; rf < 4; ++rf) {
        const int ob = w * 64 + rf * 16 + (lane >> 4) * 4;  // o base (mult of 4)
        #pragma unroll
        for (int cf = 0; cf < 4; ++cf) {
            const int hw = hw0 + cf * 16 + (lane & 15);
            size_t idx = fragidx(b, ob, hw);
            {   // Q
                float v0 = accQ[rf][cf][0] + bq[ob + 0];
                float v1 = accQ[rf][cf][1] + bq[ob + 1];
                float v2 = accQ[rf][cf][2] + bq[ob + 2];
                float v3 = accQ[rf][cf][3] + bq[ob + 3];
                int u = __builtin_amdgcn_cvt_pk_fp8_f32(v0, v1, 0, false);
                u = __builtin_amdgcn_cvt_pk_fp8_f32(v2, v3, u, true);
                *(unsigned int*)&Qw8[idx] = (unsigned int)u;
                qmx[cf][0] = fmaxf(qmx[cf][0], v0);
                qmx[cf][1] = fmaxf(qmx[cf][1], v1);
                qmx[cf][2] = fmaxf(qmx[cf][2], v2);
                qmx[cf][3] = fmaxf(qmx[cf][3], v3);
            }
            {   // K
                float v0 = accK[rf][cf][0] + bk[ob + 0];
                float v1 = accK[rf][cf][1] + bk[ob + 1];
                float v2 = accK[rf][cf][2] + bk[ob + 2];
                float v3 = accK[rf][cf][3] + bk[ob + 3];
                int u = __builtin_amdgcn_cvt_pk_fp8_f32(v0, v1, 0, false);
                u = __builtin_amdgcn_cvt_pk_fp8_f32(v2, v3, u, true);
                *(unsigned int*)&Kw8[idx] = (unsigned int)u;
            }
        }
    }
    // Q_mask reduce: lanes l, l^16, l^32, l^48 share hw col & class r
    #pragma unroll
    for (int cf = 0; cf < 4; ++cf)
        #pragma unroll
        for (int r = 0; r < 4; ++r) {
            float v = qmx[cf][r];
            v = fmaxf(v, __shfl_xor(v, 16));
            v = fmaxf(v, __shfl_xor(v, 32));
            qmx[cf][r] = v;
        }
    __syncthreads();
    if (lane < 16) {
        #pragma unroll
        for (int cf = 0; cf < 4; ++cf)
            #pragma unroll
            for (int r = 0; r < 4; ++r)
                qred[w][r][cf * 16 + lane] = qmx[cf][r];
    }
    __syncthreads();
    {
        const int r = t >> 6, h64 = t & 63;
        float v = fmaxf(fmaxf(qred[0][r][h64], qred[1][r][h64]),
                        fmaxf(qred[2][r][h64], qred[3][r][h64]));
        atomicMax(qmout + r * HW + hw0 + h64, fkey(v));
    }
}

// ---------------------------------------------------------------------------
// V conv + mask epilogue, reading fuse directly (same transposing stage).
__global__ __launch_bounds__(256) void convV_kernel(
    const float* __restrict__ fuse, const ushort* __restrict__ Wv16,
    const float* __restrict__ bv, float* __restrict__ outf,
    const unsigned int* __restrict__ m2key,
    const unsigned int* __restrict__ qmkey) {
    __shared__ __align__(16) ushort Als[256][72];
    __shared__ __align__(16) float tileF[64][65];
    __shared__ __align__(16) ushort Bls[64][72];
    __shared__ float m2s[64];
    const int t = threadIdx.x;
    const int lane = t & 63, w = t >> 6;
    const int hw0 = blockIdx.x * 64;
    const int b = blockIdx.y;
    if (t < 64) m2s[t] = __uint_as_float(m2key[b * 64 + t]);
    f32x4 acc[4][4] = {};
    for (int kc = 0; kc < 4; ++kc) {
        __syncthreads();
        #pragma unroll
        for (int i = 0; i < 8; ++i) {
            int q = t + 256 * i;
            int row = q >> 3, c8 = (q & 7) * 8;
            *(int4*)&Als[row][c8] =
                *(const int4*)(Wv16 + (size_t)row * CH + kc * 64 + c8);
        }
        {
            const int c = t >> 2, q4 = (t & 3) * 16;
            const float* src = fuse + ((size_t)b * CH + kc * 64 + c) * HW + hw0 + q4;
            #pragma unroll
            for (int q = 0; q < 4; ++q) {
                float4 v = *(const float4*)(src + q * 4);
                tileF[c][q4 + q * 4 + 0] = v.x; tileF[c][q4 + q * 4 + 1] = v.y;
                tileF[c][q4 + q * 4 + 2] = v.z; tileF[c][q4 + q * 4 + 3] = v.w;
            }
        }
        __syncthreads();
        #pragma unroll
        for (int rep = 0; rep < 2; ++rep) {
            int u = t + rep * 256;
            int hw = u >> 3, i8 = (u & 7) * 8;
            __align__(16) ushort o8[8];
            #pragma unroll
            for (int k = 0; k < 8; ++k) o8[k] = f2bf(tileF[i8 + k][hw]);
            *(int4*)&Bls[hw][i8] = *(const int4*)o8;
        }
        __syncthreads();
        #pragma unroll
        for (int kk = 0; kk < 2; ++kk) {
            bf16x8 af[4];
            #pragma unroll
            for (int rf = 0; rf < 4; ++rf)
                af[rf] = *(const bf16x8*)&Als[w * 64 + rf * 16 + (lane & 15)]
                                             [kk * 32 + (lane >> 4) * 8];
            #pragma unroll
            for (int cf = 0; cf < 4; ++cf) {
                bf16x8 bf_ = *(const bf16x8*)&Bls[cf * 16 + (lane & 15)]
                                                 [kk * 32 + (lane >> 4) * 8];
                #pragma unroll
                for (int rf = 0; rf < 4; ++rf)
                    acc[rf][cf] = __builtin_amdgcn_mfma_f32_16x16x32_bf16(
                        af[rf], bf_, acc[rf][cf], 0, 0, 0);
            }
        }
    }
    #pragma unroll
    for (int rf = 0; rf < 4; ++rf) {
        const int ob = w * 64 + rf * 16 + (lane >> 4) * 4;
        #pragma unroll
        for (int cf = 0; cf < 4; ++cf) {
            const int hw = hw0 + cf * 16 + (lane & 15);
            const float mv = m2s[ob >> 2];
            #pragma unroll
            for (int r = 0; r < 4; ++r) {   // o = ob+r, o%4 == r
                float vv = acc[rf][cf][r] + bv[ob + r];
                float qm = finv(qmkey[r * HW + hw]);
                outf[((size_t)b * CH + ob + r) * HW + hw] = vv * (1.0f + mv * qm);
            }
        }
    }
}

// ---------------------------------------------------------------------------
// scores64 (R13 structure + BURST LOADS): 64n x 64m tile, 4 waves = 4
// batches. __launch_bounds__(256,2) gives the allocator ~256 regs/wave
// (R6-R13 the compiler pinned VGPR to ~56-60 -> only ~2 loads in flight,
// ~10x latency exposure). Now ALL 32 pair-loads are hoisted into named
// register arrays (static indexing), sched_barrier pins the burst before
// the MFMA block: latency is paid once per tile, not per kc.
__global__ __launch_bounds__(256, 2) void scores64(
    const u8* __restrict__ Qw, const u8* __restrict__ Kw,
    unsigned int* __restrict__ m2k) {
    __shared__ __align__(16) f32x4 EX[4][4][64];   // [b][mf][lane] 16 KB
    __shared__ float red[4][4];                    // [wave][batch]
    const int t = threadIdx.x;
    const int lane = t & 63, w = t >> 6;           // w = batch
    // XCD-rectangle swizzle: xcd gets 16n x 32m tiles (Q 1MB + K 2MB < 4MB L2)
    const int bid = blockIdx.x;
    const int xcd = bid & 7, j = bid >> 3;
    const int vn = (xcd & 3) * 16 + (j & 15);
    const int vm = (xcd >> 2) * 32 + (j >> 4);

    // pair-region bases: pair (b, kc, pairblk) is 1KB; tile has 2 pairs
    const u8* qp = Qw + (((size_t)w * 8) * 128 + vn * 2) * 1024 + lane * 16;
    const u8* kp = Kw + (((size_t)w * 8) * 128 + vm * 2) * 1024 + lane * 16;

    // burst: all 32 loads issued back-to-back (128 VGPR of data in flight)
    longx2 AQ[8][2], BK[8][2];
    #pragma unroll
    for (int kc = 0; kc < 8; ++kc) {
        #pragma unroll
        for (int p = 0; p < 2; ++p) {
            AQ[kc][p] = *(const longx2*)(qp + (size_t)kc * 131072 + p * 1024);
            BK[kc][p] = *(const longx2*)(kp + (size_t)kc * 131072 + p * 1024);
        }
    }
    __builtin_amdgcn_sched_barrier(0);   // keep the burst ahead of the MFMAs

    f32x4 acc[4][4] = {};   // [nf][mf]
    #pragma unroll
    for (int kc = 0; kc < 8; ++kc) {
        #pragma unroll
        for (int mf = 0; mf < 4; ++mf) {
            long bf_ = BK[kc][mf >> 1][mf & 1];
            #pragma unroll
            for (int nf = 0; nf < 4; ++nf)
                acc[nf][mf] = __builtin_amdgcn_mfma_f32_16x16x32_fp8_fp8(
                    AQ[kc][nf >> 1][nf & 1], bf_, acc[nf][mf], 0, 0, 0);
        }
    }

    // ---- exchange + softmax: 4 substeps over nf ----
    float pmAll[4] = {0.f, 0.f, 0.f, 0.f};
    #pragma unroll
    for (int nf = 0; nf < 4; ++nf) {
        if (nf) __syncthreads();          // previous substep's reads done
        #pragma unroll
        for (int mf = 0; mf < 4; ++mf)
            EX[w][mf][lane] = acc[nf][mf];
        __syncthreads();
        f32x4 sv[4];
        #pragma unroll
        for (int b2 = 0; b2 < 4; ++b2)
            sv[b2] = EX[b2][w][lane];     // this thread owns mf = w
        #pragma unroll
        for (int jj = 0; jj < 4; ++jj) {
            float e0 = __expf(sv[0][jj] * 0.0625f);
            float e1 = __expf(sv[1][jj] * 0.0625f);
            float e2 = __expf(sv[2][jj] * 0.0625f);
            float e3 = __expf(sv[3][jj] * 0.0625f);
            float inv = __fdividef(1.0f, e0 + e1 + e2 + e3);
            pmAll[0] = fmaxf(pmAll[0], e0 * inv);
            pmAll[1] = fmaxf(pmAll[1], e1 * inv);
            pmAll[2] = fmaxf(pmAll[2], e2 * inv);
            pmAll[3] = fmaxf(pmAll[3], e3 * inv);
        }
    }
    // wave reduce (max over all lanes), then block reduce, 4 atomics
    #pragma unroll
    for (int off = 32; off >= 1; off >>= 1) {
        pmAll[0] = fmaxf(pmAll[0], __shfl_xor(pmAll[0], off));
        pmAll[1] = fmaxf(pmAll[1], __shfl_xor(pmAll[1], off));
        pmAll[2] = fmaxf(pmAll[2], __shfl_xor(pmAll[2], off));
        pmAll[3] = fmaxf(pmAll[3], __shfl_xor(pmAll[3], off));
    }
    __syncthreads();   // EX reads done; red aliases fresh region anyway
    if (lane == 0) {
        #pragma unroll
        for (int b2 = 0; b2 < 4; ++b2) red[w][b2] = pmAll[b2];
    }
    __syncthreads();
    if (t < 4) {   // t = batch
        float v = fmaxf(fmaxf(red[0][t], red[1][t]),
                        fmaxf(red[2][t], red[3][t]));
        atomicMax(m2k + t * 64 + vm, __float_as_uint(v));  // soft > 0
    }
}

// ---------------------------------------------------------------------------
extern "C" void kernel_launch(void* const* d_in, const int* in_sizes, int n_in,
                              void* d_out, int out_size, void* d_ws, size_t ws_size,
                              hipStream_t stream) {
    const float* fuse = (const float*)d_in[0];
    const float* Wq   = (const float*)d_in[1];
    const float* bq   = (const float*)d_in[2];
    const float* Wk   = (const float*)d_in[3];
    const float* bk   = (const float*)d_in[4];
    const float* Wv   = (const float*)d_in[5];
    const float* bv   = (const float*)d_in[6];
    float* out = (float*)d_out;

    char* ws = (char*)d_ws;
    ushort* Wq16  = (ushort*)(ws);                      // 128 KiB
    ushort* Wk16  = (ushort*)(ws + 131072);             // 128 KiB
    ushort* Wv16  = (ushort*)(ws + 262144);             // 128 KiB
    u8*     Qw8   = (u8*)    (ws + 393216);             // 4 MiB (fp8 pair-frag)
    u8*     Kw8   = (u8*)    (ws + 4587520);            // 4 MiB (fp8 pair-frag)
    unsigned int* QMK = (unsigned int*)(ws + 8781824);  // 64 KiB (Q_mask keys)
    unsigned int* M2K = (unsigned int*)(ws + 8847360);  // 1 KiB (m2 keys)

    prep_kernel<<<256, 256, 0, stream>>>(Wq, Wk, Wv, Wq16, Wk16, Wv16, M2K, QMK);
    convQK_kernel<<<dim3(64, NB), 256, 0, stream>>>(
        fuse, Wq16, Wk16, bq, bk, Qw8, Kw8, QMK);
    scores64<<<4096, 256, 0, stream>>>(Qw8, Kw8, M2K);
    convV_kernel<<<dim3(64, NB), 256, 0, stream>>>(
        fuse, Wv16, bv, out, M2K, QMK);
}

// Round 15
// 72.034 us; speedup vs baseline: 2.3814x; 1.0341x over previous
//
#include <hip/hip_runtime.h>
#include <stdint.h>

#define HW 4096
#define CH 256
#define NB 4

typedef __attribute__((ext_vector_type(8))) short bf16x8;
typedef __attribute__((ext_vector_type(4))) float f32x4;
typedef __attribute__((ext_vector_type(2))) long longx2;
typedef unsigned char u8;

__device__ __forceinline__ ushort f2bf(float f) {
    uint32_t u = __float_as_uint(f);
    u += 0x7fffu + ((u >> 16) & 1u);   // RNE
    return (ushort)(u >> 16);
}
// monotone float<->uint key (handles negatives) for atomicMax reductions
__device__ __forceinline__ uint fkey(float f) {
    uint b = __float_as_uint(f);
    return ((int)b < 0) ? ~b : (b | 0x80000000u);
}
__device__ __forceinline__ float finv(uint k) {
    uint b = (k & 0x80000000u) ? (k ^ 0x80000000u) : ~k;
    return __uint_as_float(b);
}

// fp8 fragment-PAIR index: fragments for adjacent 16-hw blocks are
// interleaved per-lane (lane's 16B = 8B of even frag || 8B of odd frag),
// so ONE dwordx4 wave-load feeds TWO MFMA operands.
__device__ __forceinline__ size_t fragidx(int b, int o, int hw) {
    return ((((size_t)b * 8 + (o >> 5)) * 128 + (hw >> 5)) * 1024)
         + ((((o >> 3) & 3) * 16 + (hw & 15)) * 16)
         + (((hw >> 4) & 1) * 8) + (o & 7);
}

// ---------------------------------------------------------------------------
// prep: convert 3 weight matrices fp32->bf16, zero m2/Qmask key accumulators
__global__ __launch_bounds__(256) void prep_kernel(
    const float* __restrict__ Wq, const float* __restrict__ Wk,
    const float* __restrict__ Wv,
    ushort* __restrict__ Wq16, ushort* __restrict__ Wk16,
    ushort* __restrict__ Wv16, unsigned int* __restrict__ m2k,
    unsigned int* __restrict__ qmk) {
    int i = blockIdx.x * 256 + threadIdx.x;   // grid covers 65536
    Wq16[i] = f2bf(Wq[i]);
    Wk16[i] = f2bf(Wk[i]);
    Wv16[i] = f2bf(Wv[i]);
    if (i < NB * HW) qmk[i] = 0;              // fkey-min
    if (i < NB * 64) m2k[i] = 0;              // positive-float-min
}

// ---------------------------------------------------------------------------
// Fused Q+K conv1x1, reading fuse DIRECTLY (transposing LDS stage).
// Outputs: Qw8/Kw8 fp8 e4m3 pair-packed fragment-major + Q_mask reduce.
__global__ __launch_bounds__(256) void convQK_kernel(
    const float* __restrict__ fuse,
    const ushort* __restrict__ Wq16, const ushort* __restrict__ Wk16,
    const float* __restrict__ bq, const float* __restrict__ bk,
    u8* __restrict__ Qw8, u8* __restrict__ Kw8,
    unsigned int* __restrict__ qmout) {
    __shared__ __align__(16) ushort WqLs[256][72];
    __shared__ __align__(16) ushort WkLs[256][72];
    __shared__ __align__(16) float tileF[64][65];
    __shared__ __align__(16) ushort Bls[64][72];
    __shared__ float qred[4][4][64];
    const int t = threadIdx.x;
    const int lane = t & 63, w = t >> 6;
    const int hw0 = blockIdx.x * 64;
    const int b = blockIdx.y;
    f32x4 accQ[4][4] = {}, accK[4][4] = {};   // [rf(o)][cf(hw)]
    for (int kc = 0; kc < 4; ++kc) {
        __syncthreads();
        #pragma unroll
        for (int i = 0; i < 8; ++i) {
            int q = t + 256 * i;
            int row = q >> 3, c8 = (q & 7) * 8;
            *(int4*)&WqLs[row][c8] =
                *(const int4*)(Wq16 + (size_t)row * CH + kc * 64 + c8);
            *(int4*)&WkLs[row][c8] =
                *(const int4*)(Wk16 + (size_t)row * CH + kc * 64 + c8);
        }
        {   // stage fuse[b][kc*64 + c][hw0..64] -> tileF[c][hw] (coalesced)
            const int c = t >> 2, q4 = (t & 3) * 16;
            const float* src = fuse + ((size_t)b * CH + kc * 64 + c) * HW + hw0 + q4;
            #pragma unroll
            for (int q = 0; q < 4; ++q) {
                float4 v = *(const float4*)(src + q * 4);
                tileF[c][q4 + q * 4 + 0] = v.x; tileF[c][q4 + q * 4 + 1] = v.y;
                tileF[c][q4 + q * 4 + 2] = v.z; tileF[c][q4 + q * 4 + 3] = v.w;
            }
        }
        __syncthreads();
        #pragma unroll
        for (int rep = 0; rep < 2; ++rep) {   // tileF -> Bls[hw][c] bf16
            int u = t + rep * 256;
            int hw = u >> 3, i8 = (u & 7) * 8;
            __align__(16) ushort o8[8];
            #pragma unroll
            for (int k = 0; k < 8; ++k) o8[k] = f2bf(tileF[i8 + k][hw]);
            *(int4*)&Bls[hw][i8] = *(const int4*)o8;
        }
        __syncthreads();
        #pragma unroll
        for (int kk = 0; kk < 2; ++kk) {
            bf16x8 aq[4], ak[4];
            #pragma unroll
            for (int rf = 0; rf < 4; ++rf) {
                aq[rf] = *(const bf16x8*)&WqLs[w * 64 + rf * 16 + (lane & 15)]
                                              [kk * 32 + (lane >> 4) * 8];
                ak[rf] = *(const bf16x8*)&WkLs[w * 64 + rf * 16 + (lane & 15)]
                                              [kk * 32 + (lane >> 4) * 8];
            }
            #pragma unroll
            for (int cf = 0; cf < 4; ++cf) {
                bf16x8 bf_ = *(const bf16x8*)&Bls[cf * 16 + (lane & 15)]
                                                 [kk * 32 + (lane >> 4) * 8];
                #pragma unroll
                for (int rf = 0; rf < 4; ++rf) {
                    accQ[rf][cf] = __builtin_amdgcn_mfma_f32_16x16x32_bf16(
                        aq[rf], bf_, accQ[rf][cf], 0, 0, 0);
                    accK[rf][cf] = __builtin_amdgcn_mfma_f32_16x16x32_bf16(
                        ak[rf], bf_, accK[rf][cf], 0, 0, 0);
                }
            }
        }
    }
    float qmx[4][4];   // [cf][r] running max for Q_mask
    #pragma unroll
    for (int cf = 0; cf < 4; ++cf)
        #pragma unroll
        for (int r = 0; r < 4; ++r) qmx[cf][r] = -3.4e38f;
    #pragma unroll
    for (int rf = 0; rf < 4; ++rf) {
        const int ob = w * 64 + rf * 16 + (lane >> 4) * 4;  // o base (mult of 4)
        #pragma unroll
        for (int cf = 0; cf < 4; ++cf) {
            const int hw = hw0 + cf * 16 + (lane & 15);
            size_t idx = fragidx(b, ob, hw);
            {   // Q
                float v0 = accQ[rf][cf][0] + bq[ob + 0];
                float v1 = accQ[rf][cf][1] + bq[ob + 1];
                float v2 = accQ[rf][cf][2] + bq[ob + 2];
                float v3 = accQ[rf][cf][3] + bq[ob + 3];
                int u = __builtin_amdgcn_cvt_pk_fp8_f32(v0, v1, 0, false);
                u = __builtin_amdgcn_cvt_pk_fp8_f32(v2, v3, u, true);
                *(unsigned int*)&Qw8[idx] = (unsigned int)u;
                qmx[cf][0] = fmaxf(qmx[cf][0], v0);
                qmx[cf][1] = fmaxf(qmx[cf][1], v1);
                qmx[cf][2] = fmaxf(qmx[cf][2], v2);
                qmx[cf][3] = fmaxf(qmx[cf][3], v3);
            }
            {   // K
                float v0 = accK[rf][cf][0] + bk[ob + 0];
                float v1 = accK[rf][cf][1] + bk[ob + 1];
                float v2 = accK[rf][cf][2] + bk[ob + 2];
                float v3 = accK[rf][cf][3] + bk[ob + 3];
                int u = __builtin_amdgcn_cvt_pk_fp8_f32(v0, v1, 0, false);
                u = __builtin_amdgcn_cvt_pk_fp8_f32(v2, v3, u, true);
                *(unsigned int*)&Kw8[idx] = (unsigned int)u;
            }
        }
    }
    // Q_mask reduce: lanes l, l^16, l^32, l^48 share hw col & class r
    #pragma unroll
    for (int cf = 0; cf < 4; ++cf)
        #pragma unroll
        for (int r = 0; r < 4; ++r) {
            float v = qmx[cf][r];
            v = fmaxf(v, __shfl_xor(v, 16));
            v = fmaxf(v, __shfl_xor(v, 32));
            qmx[cf][r] = v;
        }
    __syncthreads();
    if (lane < 16) {
        #pragma unroll
        for (int cf = 0; cf < 4; ++cf)
            #pragma unroll
            for (int r = 0; r < 4; ++r)
                qred[w][r][cf * 16 + lane] = qmx[cf][r];
    }
    __syncthreads();
    {
        const int r = t >> 6, h64 = t & 63;
        float v = fmaxf(fmaxf(qred[0][r][h64], qred[1][r][h64]),
                        fmaxf(qred[2][r][h64], qred[3][r][h64]));
        atomicMax(qmout + r * HW + hw0 + h64, fkey(v));
    }
}

// ---------------------------------------------------------------------------
// V conv + mask epilogue, reading fuse directly (same transposing stage).
__global__ __launch_bounds__(256) void convV_kernel(
    const float* __restrict__ fuse, const ushort* __restrict__ Wv16,
    const float* __restrict__ bv, float* __restrict__ outf,
    const unsigned int* __restrict__ m2key,
    const unsigned int* __restrict__ qmkey) {
    __shared__ __align__(16) ushort Als[256][72];
    __shared__ __align__(16) float tileF[64][65];
    __shared__ __align__(16) ushort Bls[64][72];
    __shared__ float m2s[64];
    const int t = threadIdx.x;
    const int lane = t & 63, w = t >> 6;
    const int hw0 = blockIdx.x * 64;
    const int b = blockIdx.y;
    if (t < 64) m2s[t] = __uint_as_float(m2key[b * 64 + t]);
    f32x4 acc[4][4] = {};
    for (int kc = 0; kc < 4; ++kc) {
        __syncthreads();
        #pragma unroll
        for (int i = 0; i < 8; ++i) {
            int q = t + 256 * i;
            int row = q >> 3, c8 = (q & 7) * 8;
            *(int4*)&Als[row][c8] =
                *(const int4*)(Wv16 + (size_t)row * CH + kc * 64 + c8);
        }
        {
            const int c = t >> 2, q4 = (t & 3) * 16;
            const float* src = fuse + ((size_t)b * CH + kc * 64 + c) * HW + hw0 + q4;
            #pragma unroll
            for (int q = 0; q < 4; ++q) {
                float4 v = *(const float4*)(src + q * 4);
                tileF[c][q4 + q * 4 + 0] = v.x; tileF[c][q4 + q * 4 + 1] = v.y;
                tileF[c][q4 + q * 4 + 2] = v.z; tileF[c][q4 + q * 4 + 3] = v.w;
            }
        }
        __syncthreads();
        #pragma unroll
        for (int rep = 0; rep < 2; ++rep) {
            int u = t + rep * 256;
            int hw = u >> 3, i8 = (u & 7) * 8;
            __align__(16) ushort o8[8];
            #pragma unroll
            for (int k = 0; k < 8; ++k) o8[k] = f2bf(tileF[i8 + k][hw]);
            *(int4*)&Bls[hw][i8] = *(const int4*)o8;
        }
        __syncthreads();
        #pragma unroll
        for (int kk = 0; kk < 2; ++kk) {
            bf16x8 af[4];
            #pragma unroll
            for (int rf = 0; rf < 4; ++rf)
                af[rf] = *(const bf16x8*)&Als[w * 64 + rf * 16 + (lane & 15)]
                                             [kk * 32 + (lane >> 4) * 8];
            #pragma unroll
            for (int cf = 0; cf < 4; ++cf) {
                bf16x8 bf_ = *(const bf16x8*)&Bls[cf * 16 + (lane & 15)]
                                                 [kk * 32 + (lane >> 4) * 8];
                #pragma unroll
                for (int rf = 0; rf < 4; ++rf)
                    acc[rf][cf] = __builtin_amdgcn_mfma_f32_16x16x32_bf16(
                        af[rf], bf_, acc[rf][cf], 0, 0, 0);
            }
        }
    }
    #pragma unroll
    for (int rf = 0; rf < 4; ++rf) {
        const int ob = w * 64 + rf * 16 + (lane >> 4) * 4;
        #pragma unroll
        for (int cf = 0; cf < 4; ++cf) {
            const int hw = hw0 + cf * 16 + (lane & 15);
            const float mv = m2s[ob >> 2];
            #pragma unroll
            for (int r = 0; r < 4; ++r) {   // o = ob+r, o%4 == r
                float vv = acc[rf][cf][r] + bv[ob + r];
                float qm = finv(qmkey[r * HW + hw]);
                outf[((size_t)b * CH + ob + r) * HW + hw] = vv * (1.0f + mv * qm);
            }
        }
    }
}

// ---------------------------------------------------------------------------
// scores64 PERSISTENT M-STRIP: 512 blocks (2/CU, fully resident). Block owns
// ONE vm (K column panel) and a strip of 8 vn tiles. Wins vs R14:
//  (1) K fragments loaded ONCE into registers (BK, 64 VGPR) -- per-tile
//      global chains halve to Q-only (16), K refetch traffic gone;
//  (2) Q(i+1) prefetch issues right after MFMA(i) consumes AQ (WAR-safe by
//      in-order issue) -> L2 latency hides under tile i's epilogue;
//  (3) single-shot EX (64 KB, [b][nf][mf][lane]) -> 2 barriers/tile (was 8);
//      pmAll accumulates across the strip -> ONE atomic per block.
__global__ __launch_bounds__(256, 2) void scores64(
    const u8* __restrict__ Qw, const u8* __restrict__ Kw,
    unsigned int* __restrict__ m2k) {
    __shared__ __align__(16) f32x4 EX[4][4][4][64];   // [b][nf][mf][lane] 64 KB
    __shared__ float red[4][4];                       // [wave][batch]
    const int t = threadIdx.x;
    const int lane = t & 63, w = t >> 6;              // w = batch
    // 512 blocks: xcd owns vm range [xcd*8, xcd*8+8), all 8 n-strips
    const int bid = blockIdx.x;
    const int xcd = bid & 7, j = bid >> 3;
    const int vm = xcd * 8 + (j & 7);
    const int s  = j >> 3;                            // n-strip: vn = s*8+it

    const u8* kp = Kw + (((size_t)w * 8) * 128 + vm * 2) * 1024 + lane * 16;
    const u8* qp0 = Qw + (((size_t)w * 8) * 128 + (s * 8) * 2) * 1024 + lane * 16;

    // K resident for the whole strip
    longx2 BK[8][2];
    #pragma unroll
    for (int kc = 0; kc < 8; ++kc)
        #pragma unroll
        for (int p = 0; p < 2; ++p)
            BK[kc][p] = *(const longx2*)(kp + (size_t)kc * 131072 + p * 1024);

    longx2 AQ[8][2];
#define LOADQ(IT)                                                          \
    _Pragma("unroll") for (int kc = 0; kc < 8; ++kc)                       \
        _Pragma("unroll") for (int p = 0; p < 2; ++p)                      \
            AQ[kc][p] = *(const longx2*)(qp0 + (IT) * 2048                 \
                                         + (size_t)kc * 131072 + p * 1024);
    LOADQ(0)

    float pmAll[4] = {0.f, 0.f, 0.f, 0.f};
    #pragma unroll
    for (int it = 0; it < 8; ++it) {
        f32x4 acc[4][4] = {};   // [nf][mf]
        #pragma unroll
        for (int kc = 0; kc < 8; ++kc) {
            #pragma unroll
            for (int mf = 0; mf < 4; ++mf) {
                long bf_ = BK[kc][mf >> 1][mf & 1];
                #pragma unroll
                for (int nf = 0; nf < 4; ++nf)
                    acc[nf][mf] = __builtin_amdgcn_mfma_f32_16x16x32_fp8_fp8(
                        AQ[kc][nf >> 1][nf & 1], bf_, acc[nf][mf], 0, 0, 0);
            }
        }
        // prefetch next tile's Q while this tile's epilogue runs
        if (it + 1 < 8) { LOADQ(it + 1) }

        if (it) __syncthreads();          // prev tile's EX reads all done
        #pragma unroll
        for (int nf = 0; nf < 4; ++nf)
            #pragma unroll
            for (int mf = 0; mf < 4; ++mf)
                EX[w][nf][mf][lane] = acc[nf][mf];
        __syncthreads();
        #pragma unroll
        for (int nf = 0; nf < 4; ++nf) {
            f32x4 sv[4];
            #pragma unroll
            for (int b2 = 0; b2 < 4; ++b2)
                sv[b2] = EX[b2][nf][w][lane];   // this thread owns mf = w
            #pragma unroll
            for (int jj = 0; jj < 4; ++jj) {
                float e0 = __expf(sv[0][jj] * 0.0625f);
                float e1 = __expf(sv[1][jj] * 0.0625f);
                float e2 = __expf(sv[2][jj] * 0.0625f);
                float e3 = __expf(sv[3][jj] * 0.0625f);
                float inv = __fdividef(1.0f, e0 + e1 + e2 + e3);
                pmAll[0] = fmaxf(pmAll[0], e0 * inv);
                pmAll[1] = fmaxf(pmAll[1], e1 * inv);
                pmAll[2] = fmaxf(pmAll[2], e2 * inv);
                pmAll[3] = fmaxf(pmAll[3], e3 * inv);
            }
        }
    }
#undef LOADQ
    // strip-wide reduce: wave max, block max, ONE atomic per batch
    #pragma unroll
    for (int off = 32; off >= 1; off >>= 1) {
        pmAll[0] = fmaxf(pmAll[0], __shfl_xor(pmAll[0], off));
        pmAll[1] = fmaxf(pmAll[1], __shfl_xor(pmAll[1], off));
        pmAll[2] = fmaxf(pmAll[2], __shfl_xor(pmAll[2], off));
        pmAll[3] = fmaxf(pmAll[3], __shfl_xor(pmAll[3], off));
    }
    __syncthreads();   // EX reads done; red aliases fresh region anyway
    if (lane == 0) {
        #pragma unroll
        for (int b2 = 0; b2 < 4; ++b2) red[w][b2] = pmAll[b2];
    }
    __syncthreads();
    if (t < 4) {   // t = batch
        float v = fmaxf(fmaxf(red[0][t], red[1][t]),
                        fmaxf(red[2][t], red[3][t]));
        atomicMax(m2k + t * 64 + vm, __float_as_uint(v));  // soft > 0
    }
}

// ---------------------------------------------------------------------------
extern "C" void kernel_launch(void* const* d_in, const int* in_sizes, int n_in,
                              void* d_out, int out_size, void* d_ws, size_t ws_size,
                              hipStream_t stream) {
    const float* fuse = (const float*)d_in[0];
    const float* Wq   = (const float*)d_in[1];
    const float* bq   = (const float*)d_in[2];
    const float* Wk   = (const float*)d_in[3];
    const float* bk   = (const float*)d_in[4];
    const float* Wv   = (const float*)d_in[5];
    const float* bv   = (const float*)d_in[6];
    float* out = (float*)d_out;

    char* ws = (char*)d_ws;
    ushort* Wq16  = (ushort*)(ws);                      // 128 KiB
    ushort* Wk16  = (ushort*)(ws + 131072);             // 128 KiB
    ushort* Wv16  = (ushort*)(ws + 262144);             // 128 KiB
    u8*     Qw8   = (u8*)    (ws + 393216);             // 4 MiB (fp8 pair-frag)
    u8*     Kw8   = (u8*)    (ws + 4587520);            // 4 MiB (fp8 pair-frag)
    unsigned int* QMK = (unsigned int*)(ws + 8781824);  // 64 KiB (Q_mask keys)
    unsigned int* M2K = (unsigned int*)(ws + 8847360);  // 1 KiB (m2 keys)

    prep_kernel<<<256, 256, 0, stream>>>(Wq, Wk, Wv, Wq16, Wk16, Wv16, M2K, QMK);
    convQK_kernel<<<dim3(64, NB), 256, 0, stream>>>(
        fuse, Wq16, Wk16, bq, bk, Qw8, Kw8, QMK);
    scores64<<<512, 256, 0, stream>>>(Qw8, Kw8, M2K);
    convV_kernel<<<dim3(64, NB), 256, 0, stream>>>(
        fuse, Wv16, bv, out, M2K, QMK);
}

// Round 16
// 65.912 us; speedup vs baseline: 2.6026x; 1.0929x over previous
//
#include <hip/hip_runtime.h>
#include <stdint.h>

#define HW 4096
#define CH 256
#define NB 4

typedef __attribute__((ext_vector_type(8))) short bf16x8;
typedef __attribute__((ext_vector_type(4))) float f32x4;
typedef __attribute__((ext_vector_type(2))) long longx2;
typedef unsigned char u8;

__device__ __forceinline__ ushort f2bf(float f) {
    uint32_t u = __float_as_uint(f);
    u += 0x7fffu + ((u >> 16) & 1u);   // RNE
    return (ushort)(u >> 16);
}
// monotone float<->uint key (handles negatives) for atomicMax reductions
__device__ __forceinline__ uint fkey(float f) {
    uint b = __float_as_uint(f);
    return ((int)b < 0) ? ~b : (b | 0x80000000u);
}
__device__ __forceinline__ float finv(uint k) {
    uint b = (k & 0x80000000u) ? (k ^ 0x80000000u) : ~k;
    return __uint_as_float(b);
}
// force a value to stay materialized in VGPRs (defeats rematerialization)
__device__ __forceinline__ void keepl(longx2& v) { asm volatile("" : "+v"(v)); }

// raw barrier: LDS-ordering only, does NOT drain vmcnt (keeps prefetch alive)
#define LGK_BAR()                                                        \
    do {                                                                 \
        asm volatile("s_waitcnt lgkmcnt(0)" ::: "memory");               \
        __builtin_amdgcn_sched_barrier(0);                               \
        asm volatile("s_barrier" ::: "memory");                          \
    } while (0)

// fp8 fragment-PAIR index (scores operands): lane's 16B = 8B even frag ||
// 8B odd frag, so one dwordx4 wave-load feeds TWO MFMA operands.
__device__ __forceinline__ size_t fragidx(int b, int o, int hw) {
    return ((((size_t)b * 8 + (o >> 5)) * 128 + (hw >> 5)) * 1024)
         + ((((o >> 3) & 3) * 16 + (hw & 15)) * 16)
         + (((hw >> 4) & 1) * 8) + (o & 7);
}
// bf16 A-fragment-packed weight index (conv A operands): block
// (c>>5, o>>4) is 1KB contiguous; lane = ((c>>3)&3)*16 + (o&15), elem c&7.
__device__ __forceinline__ int wpackidx(int o, int c) {
    return (((c >> 5) * 16 + (o >> 4)) * 64 + ((c >> 3) & 3) * 16 + (o & 15)) * 8
         + (c & 7);
}

// ---------------------------------------------------------------------------
// prep: weights fp32 -> bf16 in A-FRAGMENT-PACKED order; zero m2/Qmask keys
__global__ __launch_bounds__(256) void prep_kernel(
    const float* __restrict__ Wq, const float* __restrict__ Wk,
    const float* __restrict__ Wv,
    ushort* __restrict__ Wq16, ushort* __restrict__ Wk16,
    ushort* __restrict__ Wv16, unsigned int* __restrict__ m2k,
    unsigned int* __restrict__ qmk) {
    int i = blockIdx.x * 256 + threadIdx.x;   // grid covers 65536
    int o = i >> 8, c = i & 255;
    int idx = wpackidx(o, c);
    Wq16[idx] = f2bf(Wq[i]);
    Wk16[idx] = f2bf(Wk[i]);
    Wv16[idx] = f2bf(Wv[i]);
    if (i < NB * HW) qmk[i] = 0;              // fkey-min
    if (i < NB * 64) m2k[i] = 0;              // positive-float-min
}

// ---------------------------------------------------------------------------
// Fused Q+K conv1x1: hw tile 32 (grid 512 -> 2 blocks/CU), weights via
// DIRECT coalesced global loads from packed layout (no weight LDS).
// LDS: tileF(8.4K) + Bls(4.6K), qred aliases tileF -> ~13KB total.
__global__ __launch_bounds__(256, 2) void convQK_kernel(
    const float* __restrict__ fuse,
    const ushort* __restrict__ Wq16, const ushort* __restrict__ Wk16,
    const float* __restrict__ bq, const float* __restrict__ bk,
    u8* __restrict__ Qw8, u8* __restrict__ Kw8,
    unsigned int* __restrict__ qmout) {
    __shared__ __align__(16) char cpool[13056];
    float (*tileF)[33]   = (float(*)[33])cpool;             // [64][33] f32
    ushort (*Bls)[72]    = (ushort(*)[72])(cpool + 8448);   // [32][72]
    float (*qred)[4][32] = (float(*)[4][32])cpool;          // alias tileF
    const int t = threadIdx.x;
    const int lane = t & 63, w = t >> 6;
    const int hw0 = blockIdx.x * 32;
    const int b = blockIdx.y;
    f32x4 accQ[4][2] = {}, accK[4][2] = {};   // [rf(o)][cf(hw)]
    for (int kc = 0; kc < 4; ++kc) {
        __syncthreads();
        {   // stage fuse[b][kc*64+c][hw0..32] -> tileF[c][hw]
            const int c = t >> 2, h8 = (t & 3) * 8;
            const float* src = fuse + ((size_t)b * CH + kc * 64 + c) * HW + hw0 + h8;
            #pragma unroll
            for (int q = 0; q < 2; ++q) {
                float4 v = *(const float4*)(src + q * 4);
                tileF[c][h8 + q * 4 + 0] = v.x; tileF[c][h8 + q * 4 + 1] = v.y;
                tileF[c][h8 + q * 4 + 2] = v.z; tileF[c][h8 + q * 4 + 3] = v.w;
            }
        }
        __syncthreads();
        {   // tileF -> Bls[hw][c] bf16 (transposed)
            const int hw = t >> 3, i8 = (t & 7) * 8;
            __align__(16) ushort o8[8];
            #pragma unroll
            for (int k = 0; k < 8; ++k) o8[k] = f2bf(tileF[i8 + k][hw]);
            *(int4*)&Bls[hw][i8] = *(const int4*)o8;
        }
        __syncthreads();
        #pragma unroll
        for (int kk = 0; kk < 2; ++kk) {
            bf16x8 aq[4], ak[4];
            const int fb = ((kc * 2 + kk) * 16 + w * 4) * 512 + lane * 8;
            #pragma unroll
            for (int rf = 0; rf < 4; ++rf) {
                aq[rf] = *(const bf16x8*)(Wq16 + fb + rf * 512);
                ak[rf] = *(const bf16x8*)(Wk16 + fb + rf * 512);
            }
            #pragma unroll
            for (int cf = 0; cf < 2; ++cf) {
                bf16x8 bf_ = *(const bf16x8*)&Bls[cf * 16 + (lane & 15)]
                                                 [kk * 32 + (lane >> 4) * 8];
                #pragma unroll
                for (int rf = 0; rf < 4; ++rf) {
                    accQ[rf][cf] = __builtin_amdgcn_mfma_f32_16x16x32_bf16(
                        aq[rf], bf_, accQ[rf][cf], 0, 0, 0);
                    accK[rf][cf] = __builtin_amdgcn_mfma_f32_16x16x32_bf16(
                        ak[rf], bf_, accK[rf][cf], 0, 0, 0);
                }
            }
        }
    }
    float qmx[2][4];   // [cf][r] running max for Q_mask
    #pragma unroll
    for (int cf = 0; cf < 2; ++cf)
        #pragma unroll
        for (int r = 0; r < 4; ++r) qmx[cf][r] = -3.4e38f;
    #pragma unroll
    for (int rf = 0; rf < 4; ++rf) {
        const int ob = w * 64 + rf * 16 + (lane >> 4) * 4;  // o base (mult of 4)
        #pragma unroll
        for (int cf = 0; cf < 2; ++cf) {
            const int hw = hw0 + cf * 16 + (lane & 15);
            size_t idx = fragidx(b, ob, hw);
            {   // Q
                float v0 = accQ[rf][cf][0] + bq[ob + 0];
                float v1 = accQ[rf][cf][1] + bq[ob + 1];
                float v2 = accQ[rf][cf][2] + bq[ob + 2];
                float v3 = accQ[rf][cf][3] + bq[ob + 3];
                int u = __builtin_amdgcn_cvt_pk_fp8_f32(v0, v1, 0, false);
                u = __builtin_amdgcn_cvt_pk_fp8_f32(v2, v3, u, true);
                *(unsigned int*)&Qw8[idx] = (unsigned int)u;
                qmx[cf][0] = fmaxf(qmx[cf][0], v0);
                qmx[cf][1] = fmaxf(qmx[cf][1], v1);
                qmx[cf][2] = fmaxf(qmx[cf][2], v2);
                qmx[cf][3] = fmaxf(qmx[cf][3], v3);
            }
            {   // K
                float v0 = accK[rf][cf][0] + bk[ob + 0];
                float v1 = accK[rf][cf][1] + bk[ob + 1];
                float v2 = accK[rf][cf][2] + bk[ob + 2];
                float v3 = accK[rf][cf][3] + bk[ob + 3];
                int u = __builtin_amdgcn_cvt_pk_fp8_f32(v0, v1, 0, false);
                u = __builtin_amdgcn_cvt_pk_fp8_f32(v2, v3, u, true);
                *(unsigned int*)&Kw8[idx] = (unsigned int)u;
            }
        }
    }
    // Q_mask reduce: lanes l, l^16, l^32, l^48 share hw col & class r
    #pragma unroll
    for (int cf = 0; cf < 2; ++cf)
        #pragma unroll
        for (int r = 0; r < 4; ++r) {
            float v = qmx[cf][r];
            v = fmaxf(v, __shfl_xor(v, 16));
            v = fmaxf(v, __shfl_xor(v, 32));
            qmx[cf][r] = v;
        }
    __syncthreads();   // last tileF read long done; qred aliases it
    if (lane < 16) {
        #pragma unroll
        for (int cf = 0; cf < 2; ++cf)
            #pragma unroll
            for (int r = 0; r < 4; ++r)
                qred[w][r][cf * 16 + lane] = qmx[cf][r];
    }
    __syncthreads();
    if (t < 128) {
        const int r = t >> 5, h = t & 31;
        float v = fmaxf(fmaxf(qred[0][r][h], qred[1][r][h]),
                        fmaxf(qred[2][r][h], qred[3][r][h]));
        atomicMax(qmout + r * HW + hw0 + h, fkey(v));
    }
}

// ---------------------------------------------------------------------------
// V conv + mask epilogue: same hw-32 tiling + direct packed-weight loads.
__global__ __launch_bounds__(256, 2) void convV_kernel(
    const float* __restrict__ fuse, const ushort* __restrict__ Wv16,
    const float* __restrict__ bv, float* __restrict__ outf,
    const unsigned int* __restrict__ m2key,
    const unsigned int* __restrict__ qmkey) {
    __shared__ __align__(16) char cpool[13056];
    float (*tileF)[33] = (float(*)[33])cpool;
    ushort (*Bls)[72]  = (ushort(*)[72])(cpool + 8448);
    __shared__ float m2s[64];
    const int t = threadIdx.x;
    const int lane = t & 63, w = t >> 6;
    const int hw0 = blockIdx.x * 32;
    const int b = blockIdx.y;
    if (t < 64) m2s[t] = __uint_as_float(m2key[b * 64 + t]);
    f32x4 acc[4][2] = {};
    for (int kc = 0; kc < 4; ++kc) {
        __syncthreads();
        {
            const int c = t >> 2, h8 = (t & 3) * 8;
            const float* src = fuse + ((size_t)b * CH + kc * 64 + c) * HW + hw0 + h8;
            #pragma unroll
            for (int q = 0; q < 2; ++q) {
                float4 v = *(const float4*)(src + q * 4);
                tileF[c][h8 + q * 4 + 0] = v.x; tileF[c][h8 + q * 4 + 1] = v.y;
                tileF[c][h8 + q * 4 + 2] = v.z; tileF[c][h8 + q * 4 + 3] = v.w;
            }
        }
        __syncthreads();
        {
            const int hw = t >> 3, i8 = (t & 7) * 8;
            __align__(16) ushort o8[8];
            #pragma unroll
            for (int k = 0; k < 8; ++k) o8[k] = f2bf(tileF[i8 + k][hw]);
            *(int4*)&Bls[hw][i8] = *(const int4*)o8;
        }
        __syncthreads();
        #pragma unroll
        for (int kk = 0; kk < 2; ++kk) {
            bf16x8 af[4];
            const int fb = ((kc * 2 + kk) * 16 + w * 4) * 512 + lane * 8;
            #pragma unroll
            for (int rf = 0; rf < 4; ++rf)
                af[rf] = *(const bf16x8*)(Wv16 + fb + rf * 512);
            #pragma unroll
            for (int cf = 0; cf < 2; ++cf) {
                bf16x8 bf_ = *(const bf16x8*)&Bls[cf * 16 + (lane & 15)]
                                                 [kk * 32 + (lane >> 4) * 8];
                #pragma unroll
                for (int rf = 0; rf < 4; ++rf)
                    acc[rf][cf] = __builtin_amdgcn_mfma_f32_16x16x32_bf16(
                        af[rf], bf_, acc[rf][cf], 0, 0, 0);
            }
        }
    }
    #pragma unroll
    for (int rf = 0; rf < 4; ++rf) {
        const int ob = w * 64 + rf * 16 + (lane >> 4) * 4;
        #pragma unroll
        for (int cf = 0; cf < 2; ++cf) {
            const int hw = hw0 + cf * 16 + (lane & 15);
            const float mv = m2s[ob >> 2];
            #pragma unroll
            for (int r = 0; r < 4; ++r) {   // o = ob+r, o%4 == r
                float vv = acc[rf][cf][r] + bv[ob + r];
                float qm = finv(qmkey[r * HW + hw]);
                outf[((size_t)b * CH + ob + r) * HW + hw] = vv * (1.0f + mv * qm);
            }
        }
    }
}

// ---------------------------------------------------------------------------
// scores64 persistent m-strip (R15 structure), defects fixed:
//  (a) keepl() keep-alives force BK/AQ to stay materialized in VGPRs
//      (R15: VGPR=128=BK+acc -> AQ loads were rematerialized, FETCH +50%);
//  (b) EX epilogue uses raw lgkmcnt-only barriers (no vmcnt drain), so the
//      Q(i+1) prefetch actually survives across the epilogue.
__global__ __launch_bounds__(256, 2) void scores64(
    const u8* __restrict__ Qw, const u8* __restrict__ Kw,
    unsigned int* __restrict__ m2k) {
    __shared__ __align__(16) f32x4 EX[4][4][4][64];   // [b][nf][mf][lane] 64 KB
    __shared__ float red[4][4];                       // [wave][batch]
    const int t = threadIdx.x;
    const int lane = t & 63, w = t >> 6;              // w = batch
    const int bid = blockIdx.x;
    const int xcd = bid & 7, j = bid >> 3;
    const int vm = xcd * 8 + (j & 7);
    const int s  = j >> 3;                            // n-strip: vn = s*8+it

    const u8* kp  = Kw + (((size_t)w * 8) * 128 + vm * 2) * 1024 + lane * 16;
    const u8* qp0 = Qw + (((size_t)w * 8) * 128 + (s * 8) * 2) * 1024 + lane * 16;

    // K resident for the whole strip
    longx2 BK[8][2];
    #pragma unroll
    for (int kc = 0; kc < 8; ++kc)
        #pragma unroll
        for (int p = 0; p < 2; ++p)
            BK[kc][p] = *(const longx2*)(kp + (size_t)kc * 131072 + p * 1024);
    #pragma unroll
    for (int kc = 0; kc < 8; ++kc)
        #pragma unroll
        for (int p = 0; p < 2; ++p) keepl(BK[kc][p]);

    longx2 AQ[8][2];
#define LOADQ(IT)                                                          \
    _Pragma("unroll") for (int kc = 0; kc < 8; ++kc)                       \
        _Pragma("unroll") for (int p = 0; p < 2; ++p)                      \
            AQ[kc][p] = *(const longx2*)(qp0 + (IT) * 2048                 \
                                         + (size_t)kc * 131072 + p * 1024);
#define KEEPQ()                                                            \
    _Pragma("unroll") for (int kc = 0; kc < 8; ++kc)                       \
        _Pragma("unroll") for (int p = 0; p < 2; ++p) keepl(AQ[kc][p]);
    LOADQ(0)

    float pmAll[4] = {0.f, 0.f, 0.f, 0.f};
    #pragma unroll
    for (int it = 0; it < 8; ++it) {
        KEEPQ()   // materialize the prefetched tile (waitcnt lands here)
        f32x4 acc[4][4] = {};   // [nf][mf]
        #pragma unroll
        for (int kc = 0; kc < 8; ++kc) {
            #pragma unroll
            for (int mf = 0; mf < 4; ++mf) {
                long bf_ = BK[kc][mf >> 1][mf & 1];
                #pragma unroll
                for (int nf = 0; nf < 4; ++nf)
                    acc[nf][mf] = __builtin_amdgcn_mfma_f32_16x16x32_fp8_fp8(
                        AQ[kc][nf >> 1][nf & 1], bf_, acc[nf][mf], 0, 0, 0);
            }
        }
        // prefetch next tile's Q; stays in flight across the raw barriers
        if (it + 1 < 8) { LOADQ(it + 1) }

        if (it) LGK_BAR();                // prev tile's EX reads done everywhere
        #pragma unroll
        for (int nf = 0; nf < 4; ++nf)
            #pragma unroll
            for (int mf = 0; mf < 4; ++mf)
                EX[w][nf][mf][lane] = acc[nf][mf];
        LGK_BAR();                        // all EX writes visible
        #pragma unroll
        for (int nf = 0; nf < 4; ++nf) {
            f32x4 sv[4];
            #pragma unroll
            for (int b2 = 0; b2 < 4; ++b2)
                sv[b2] = EX[b2][nf][w][lane];   // this thread owns mf = w
            #pragma unroll
            for (int jj = 0; jj < 4; ++jj) {
                float e0 = __expf(sv[0][jj] * 0.0625f);
                float e1 = __expf(sv[1][jj] * 0.0625f);
                float e2 = __expf(sv[2][jj] * 0.0625f);
                float e3 = __expf(sv[3][jj] * 0.0625f);
                float inv = __fdividef(1.0f, e0 + e1 + e2 + e3);
                pmAll[0] = fmaxf(pmAll[0], e0 * inv);
                pmAll[1] = fmaxf(pmAll[1], e1 * inv);
                pmAll[2] = fmaxf(pmAll[2], e2 * inv);
                pmAll[3] = fmaxf(pmAll[3], e3 * inv);
            }
        }
    }
#undef LOADQ
#undef KEEPQ
    // strip-wide reduce: wave max, block max, ONE atomic per batch
    #pragma unroll
    for (int off = 32; off >= 1; off >>= 1) {
        pmAll[0] = fmaxf(pmAll[0], __shfl_xor(pmAll[0], off));
        pmAll[1] = fmaxf(pmAll[1], __shfl_xor(pmAll[1], off));
        pmAll[2] = fmaxf(pmAll[2], __shfl_xor(pmAll[2], off));
        pmAll[3] = fmaxf(pmAll[3], __shfl_xor(pmAll[3], off));
    }
    __syncthreads();
    if (lane == 0) {
        #pragma unroll
        for (int b2 = 0; b2 < 4; ++b2) red[w][b2] = pmAll[b2];
    }
    __syncthreads();
    if (t < 4) {   // t = batch
        float v = fmaxf(fmaxf(red[0][t], red[1][t]),
                        fmaxf(red[2][t], red[3][t]));
        atomicMax(m2k + t * 64 + vm, __float_as_uint(v));  // soft > 0
    }
}

// ---------------------------------------------------------------------------
extern "C" void kernel_launch(void* const* d_in, const int* in_sizes, int n_in,
                              void* d_out, int out_size, void* d_ws, size_t ws_size,
                              hipStream_t stream) {
    const float* fuse = (const float*)d_in[0];
    const float* Wq   = (const float*)d_in[1];
    const float* bq   = (const float*)d_in[2];
    const float* Wk   = (const float*)d_in[3];
    const float* bk   = (const float*)d_in[4];
    const float* Wv   = (const float*)d_in[5];
    const float* bv   = (const float*)d_in[6];
    float* out = (float*)d_out;

    char* ws = (char*)d_ws;
    ushort* Wq16  = (ushort*)(ws);                      // 128 KiB (A-frag packed)
    ushort* Wk16  = (ushort*)(ws + 131072);             // 128 KiB
    ushort* Wv16  = (ushort*)(ws + 262144);             // 128 KiB
    u8*     Qw8   = (u8*)    (ws + 393216);             // 4 MiB (fp8 pair-frag)
    u8*     Kw8   = (u8*)    (ws + 4587520);            // 4 MiB (fp8 pair-frag)
    unsigned int* QMK = (unsigned int*)(ws + 8781824);  // 64 KiB (Q_mask keys)
    unsigned int* M2K = (unsigned int*)(ws + 8847360);  // 1 KiB (m2 keys)

    prep_kernel<<<256, 256, 0, stream>>>(Wq, Wk, Wv, Wq16, Wk16, Wv16, M2K, QMK);
    convQK_kernel<<<dim3(128, NB), 256, 0, stream>>>(
        fuse, Wq16, Wk16, bq, bk, Qw8, Kw8, QMK);
    scores64<<<512, 256, 0, stream>>>(Qw8, Kw8, M2K);
    convV_kernel<<<dim3(128, NB), 256, 0, stream>>>(
        fuse, Wv16, bv, out, M2K, QMK);
}